// Round 1
// baseline (5688.821 us; speedup 1.0000x reference)
//
#include <hip/hip_runtime.h>
#include <hip/hip_bf16.h>
#include <math.h>

#define D_MODEL 1792
#define D_INNER 3584
#define D_STATE 16
#define D_CONV  4
#define DT_RANK 112
#define NLAYER  4
#define LSEQ    512
#define XPROJ_N (DT_RANK + 2 * D_STATE) /* 144 */

// ---------------------------------------------------------------------------
// Embedding gather: res[l, d] = embed[ids[l], d]
// ---------------------------------------------------------------------------
__global__ __launch_bounds__(256) void embed_kernel(const int* __restrict__ ids,
                                                    const float* __restrict__ embed,
                                                    float* __restrict__ res) {
    int idx = blockIdx.x * 256 + threadIdx.x;
    if (idx >= LSEQ * D_MODEL) return;
    int l = idx / D_MODEL;
    int d = idx - l * D_MODEL;
    res[idx] = embed[(size_t)ids[l] * D_MODEL + d];
}

// ---------------------------------------------------------------------------
// (optional residual += hidden) then LayerNorm over D_MODEL. One block per row.
// 1792 = 7 * 256.
// ---------------------------------------------------------------------------
__global__ __launch_bounds__(256) void add_ln_kernel(float* __restrict__ res,
                                                     const float* __restrict__ hid,
                                                     const float* __restrict__ w,
                                                     const float* __restrict__ b,
                                                     float* __restrict__ out,
                                                     int addFlag) {
    const int l = blockIdx.x;
    const int t = threadIdx.x;
    __shared__ float sbuf[8];
    float loc[7];
    float* row = res + (size_t)l * D_MODEL;

    float sum = 0.f;
#pragma unroll
    for (int i = 0; i < 7; ++i) {
        int d = t + i * 256;
        float v = row[d];
        if (addFlag) { v += hid[(size_t)l * D_MODEL + d]; row[d] = v; }
        loc[i] = v;
        sum += v;
    }
#pragma unroll
    for (int o = 32; o > 0; o >>= 1) sum += __shfl_down(sum, o, 64);
    if ((t & 63) == 0) sbuf[t >> 6] = sum;
    __syncthreads();
    if (t == 0) sbuf[4] = sbuf[0] + sbuf[1] + sbuf[2] + sbuf[3];
    __syncthreads();
    const float mu = sbuf[4] * (1.f / D_MODEL);

    float vs = 0.f;
#pragma unroll
    for (int i = 0; i < 7; ++i) { float d0 = loc[i] - mu; vs += d0 * d0; }
#pragma unroll
    for (int o = 32; o > 0; o >>= 1) vs += __shfl_down(vs, o, 64);
    __syncthreads(); // everyone has read sbuf[4]; safe to reuse
    if ((t & 63) == 0) sbuf[t >> 6] = vs;
    __syncthreads();
    if (t == 0) sbuf[4] = sbuf[0] + sbuf[1] + sbuf[2] + sbuf[3];
    __syncthreads();
    const float rstd = rsqrtf(sbuf[4] * (1.f / D_MODEL) + 1e-5f);

#pragma unroll
    for (int i = 0; i < 7; ++i) {
        int d = t + i * 256;
        out[(size_t)l * D_MODEL + d] = (loc[i] - mu) * rstd * w[d] + b[d];
    }
}

// ---------------------------------------------------------------------------
// Tiled fp32 GEMM, NT layout: C[m,n] = sum_k A[m*lda + k] * W[n*K + k]
// M always multiple of 64; K always multiple of 16; N guarded.
// act: 0 = none, 1 = softplus.  bias (indexed by n) optional.
// ---------------------------------------------------------------------------
#define GTILE 64
#define GKT   16
__global__ __launch_bounds__(256) void gemm_nt(const float* __restrict__ A, int lda,
                                               const float* __restrict__ W,
                                               float* __restrict__ C,
                                               int M, int N, int K,
                                               const float* __restrict__ bias, int act) {
    __shared__ float As[GTILE][GKT + 1];
    __shared__ float Ws[GTILE][GKT + 1];
    const int tid = threadIdx.x;
    const int m0 = blockIdx.y * GTILE;
    const int n0 = blockIdx.x * GTILE;
    const int ty = tid >> 4;   // 0..15
    const int tx = tid & 15;   // 0..15
    const int lrow = tid >> 2;       // 0..63
    const int lk4 = (tid & 3) * 4;   // 0,4,8,12

    float acc[4][4] = {};

    for (int k0 = 0; k0 < K; k0 += GKT) {
        // A tile (always in-bounds: M mult of 64, K mult of 16)
        {
            const float4 v = *reinterpret_cast<const float4*>(
                A + (size_t)(m0 + lrow) * lda + k0 + lk4);
            As[lrow][lk4 + 0] = v.x; As[lrow][lk4 + 1] = v.y;
            As[lrow][lk4 + 2] = v.z; As[lrow][lk4 + 3] = v.w;
        }
        // W tile (guard N)
        {
            const int n = n0 + lrow;
            float4 v = make_float4(0.f, 0.f, 0.f, 0.f);
            if (n < N)
                v = *reinterpret_cast<const float4*>(W + (size_t)n * K + k0 + lk4);
            Ws[lrow][lk4 + 0] = v.x; Ws[lrow][lk4 + 1] = v.y;
            Ws[lrow][lk4 + 2] = v.z; Ws[lrow][lk4 + 3] = v.w;
        }
        __syncthreads();
#pragma unroll
        for (int k = 0; k < GKT; ++k) {
            float a[4], bb[4];
#pragma unroll
            for (int i = 0; i < 4; ++i) a[i] = As[ty * 4 + i][k];
#pragma unroll
            for (int j = 0; j < 4; ++j) bb[j] = Ws[tx * 4 + j][k];
#pragma unroll
            for (int i = 0; i < 4; ++i)
#pragma unroll
                for (int j = 0; j < 4; ++j) acc[i][j] = fmaf(a[i], bb[j], acc[i][j]);
        }
        __syncthreads();
    }

#pragma unroll
    for (int i = 0; i < 4; ++i) {
        const int m = m0 + ty * 4 + i;
#pragma unroll
        for (int j = 0; j < 4; ++j) {
            const int n = n0 + tx * 4 + j;
            if (n < N) {
                float v = acc[i][j];
                if (bias) v += bias[n];
                if (act == 1) v = (v > 20.f) ? v : __logf(1.f + __expf(v));
                C[(size_t)m * N + n] = v;
            }
        }
    }
}

// ---------------------------------------------------------------------------
// Causal depthwise conv (k=4, left pad 3) + bias + SiLU.
// Input = first D_INNER columns of xz (row stride 2*D_INNER). Output xc.
// ---------------------------------------------------------------------------
__global__ __launch_bounds__(256) void conv_silu_kernel(const float* __restrict__ xz,
                                                        const float* __restrict__ cw,
                                                        const float* __restrict__ cb,
                                                        float* __restrict__ xc) {
    int idx = blockIdx.x * 256 + threadIdx.x;
    if (idx >= LSEQ * D_INNER) return;
    int l = idx / D_INNER;
    int c = idx - l * D_INNER;
    const float4 w = *reinterpret_cast<const float4*>(cw + (size_t)c * D_CONV);
    float s = cb[c];
    const float wk[4] = {w.x, w.y, w.z, w.w};
#pragma unroll
    for (int k = 0; k < D_CONV; ++k) {
        int ll = l - (D_CONV - 1) + k;
        if (ll >= 0) s = fmaf(wk[k], xz[(size_t)ll * (2 * D_INNER) + c], s);
    }
    const float sig = 1.f / (1.f + __expf(-s));
    xc[idx] = s * sig;
}

// ---------------------------------------------------------------------------
// Selective scan. One thread per channel d, 16 states in registers.
// Fuses: dA/dBx construction, scan, C-projection, D-skip, z-gate.
// Reads dt from dty and writes y back in-place (safe: same thread, same elem).
// ---------------------------------------------------------------------------
__global__ __launch_bounds__(64) void scan_kernel(float* __restrict__ dty,
                                                  const float* __restrict__ xc,
                                                  const float* __restrict__ dbl,
                                                  const float* __restrict__ A_log,
                                                  const float* __restrict__ Dp,
                                                  const float* __restrict__ xz) {
    const int d = blockIdx.x * 64 + threadIdx.x;
    __shared__ float Bs[32][D_STATE];
    __shared__ float Cs[32][D_STATE];
    float h[D_STATE], A2[D_STATE];
#pragma unroll
    for (int s = 0; s < D_STATE; ++s) {
        h[s] = 0.f;
        // dA = exp(dt*A) = exp2(dt * A * log2(e)), A = -exp(A_log)
        A2[s] = -__expf(A_log[(size_t)d * D_STATE + s]) * 1.4426950408889634f;
    }
    const float Dd = Dp[d];

    for (int l0 = 0; l0 < LSEQ; l0 += 32) {
        __syncthreads();
        for (int t = threadIdx.x; t < 32 * D_STATE; t += 64) {
            int ll = t >> 4, s = t & 15;
            Bs[ll][s] = dbl[(size_t)(l0 + ll) * XPROJ_N + DT_RANK + s];
            Cs[ll][s] = dbl[(size_t)(l0 + ll) * XPROJ_N + DT_RANK + D_STATE + s];
        }
        __syncthreads();
        for (int li = 0; li < 32; ++li) {
            const int l = l0 + li;
            const float dtv = dty[(size_t)l * D_INNER + d];
            const float xcv = xc[(size_t)l * D_INNER + d];
            const float coef = dtv * xcv;
            float a0 = 0.f, a1 = 0.f, a2 = 0.f, a3 = 0.f;
#pragma unroll
            for (int s = 0; s < D_STATE; s += 4) {
                float e0 = exp2f(dtv * A2[s + 0]);
                float e1 = exp2f(dtv * A2[s + 1]);
                float e2 = exp2f(dtv * A2[s + 2]);
                float e3 = exp2f(dtv * A2[s + 3]);
                h[s + 0] = fmaf(e0, h[s + 0], coef * Bs[li][s + 0]);
                h[s + 1] = fmaf(e1, h[s + 1], coef * Bs[li][s + 1]);
                h[s + 2] = fmaf(e2, h[s + 2], coef * Bs[li][s + 2]);
                h[s + 3] = fmaf(e3, h[s + 3], coef * Bs[li][s + 3]);
                a0 = fmaf(h[s + 0], Cs[li][s + 0], a0);
                a1 = fmaf(h[s + 1], Cs[li][s + 1], a1);
                a2 = fmaf(h[s + 2], Cs[li][s + 2], a2);
                a3 = fmaf(h[s + 3], Cs[li][s + 3], a3);
            }
            const float zv = xz[(size_t)l * (2 * D_INNER) + D_INNER + d];
            const float sig = 1.f / (1.f + __expf(-zv));
            dty[(size_t)l * D_INNER + d] = ((a0 + a1) + (a2 + a3) + Dd * xcv) * (zv * sig);
        }
    }
}

// ---------------------------------------------------------------------------
extern "C" void kernel_launch(void* const* d_in, const int* in_sizes, int n_in,
                              void* d_out, int out_size, void* d_ws, size_t ws_size,
                              hipStream_t stream) {
    const int*   ids       = (const int*)d_in[0];
    const float* embed     = (const float*)d_in[1];
    const float* in_proj_w = (const float*)d_in[2];
    const float* conv_w    = (const float*)d_in[3];
    const float* conv_b    = (const float*)d_in[4];
    const float* x_proj_w  = (const float*)d_in[5];
    const float* dt_proj_w = (const float*)d_in[6];
    const float* dt_proj_b = (const float*)d_in[7];
    const float* A_log     = (const float*)d_in[8];
    const float* D_skip    = (const float*)d_in[9];
    const float* out_proj_w= (const float*)d_in[10];
    const float* norm_w    = (const float*)d_in[11];
    const float* norm_b    = (const float*)d_in[12];
    const float* fin_w     = (const float*)d_in[13];
    const float* fin_b     = (const float*)d_in[14];
    float* out = (float*)d_out;

    float* ws = (float*)d_ws;
    float* res    = ws; ws += LSEQ * D_MODEL;
    float* hbuf   = ws; ws += LSEQ * D_MODEL;
    float* hidden = ws; ws += LSEQ * D_MODEL;
    float* xz     = ws; ws += (size_t)LSEQ * 2 * D_INNER;
    float* xc     = ws; ws += (size_t)LSEQ * D_INNER;
    float* dbl    = ws; ws += LSEQ * XPROJ_N;
    float* dty    = ws; ws += (size_t)LSEQ * D_INNER;  // dt in, y out (in-place)

    embed_kernel<<<(LSEQ * D_MODEL + 255) / 256, 256, 0, stream>>>(ids, embed, res);

    for (int i = 0; i < NLAYER; ++i) {
        add_ln_kernel<<<LSEQ, 256, 0, stream>>>(
            res, hidden, norm_w + (size_t)i * D_MODEL, norm_b + (size_t)i * D_MODEL,
            hbuf, i > 0 ? 1 : 0);

        gemm_nt<<<dim3((2 * D_INNER + GTILE - 1) / GTILE, LSEQ / GTILE), 256, 0, stream>>>(
            hbuf, D_MODEL, in_proj_w + (size_t)i * 2 * D_INNER * D_MODEL, xz,
            LSEQ, 2 * D_INNER, D_MODEL, nullptr, 0);

        conv_silu_kernel<<<(LSEQ * D_INNER + 255) / 256, 256, 0, stream>>>(
            xz, conv_w + (size_t)i * D_INNER * D_CONV, conv_b + (size_t)i * D_INNER, xc);

        gemm_nt<<<dim3((XPROJ_N + GTILE - 1) / GTILE, LSEQ / GTILE), 256, 0, stream>>>(
            xc, D_INNER, x_proj_w + (size_t)i * XPROJ_N * D_INNER, dbl,
            LSEQ, XPROJ_N, D_INNER, nullptr, 0);

        gemm_nt<<<dim3((D_INNER + GTILE - 1) / GTILE, LSEQ / GTILE), 256, 0, stream>>>(
            dbl, XPROJ_N, dt_proj_w + (size_t)i * D_INNER * DT_RANK, dty,
            LSEQ, D_INNER, DT_RANK, dt_proj_b + (size_t)i * D_INNER, 1);

        scan_kernel<<<D_INNER / 64, 64, 0, stream>>>(
            dty, xc, dbl, A_log + (size_t)i * D_INNER * D_STATE,
            D_skip + (size_t)i * D_INNER, xz);

        gemm_nt<<<dim3((D_MODEL + GTILE - 1) / GTILE, LSEQ / GTILE), 256, 0, stream>>>(
            dty, D_INNER, out_proj_w + (size_t)i * D_MODEL * D_INNER, hidden,
            LSEQ, D_MODEL, D_INNER, nullptr, 0);
    }

    add_ln_kernel<<<LSEQ, 256, 0, stream>>>(res, hidden, fin_w, fin_b, out, 1);
}

// Round 2
// 3729.519 us; speedup vs baseline: 1.5253x; 1.5253x over previous
//
#include <hip/hip_runtime.h>
#include <hip/hip_bf16.h>
#include <math.h>

#define D_MODEL 1792
#define D_INNER 3584
#define D_STATE 16
#define D_CONV  4
#define DT_RANK 112
#define NLAYER  4
#define LSEQ    512
#define XPROJ_N (DT_RANK + 2 * D_STATE) /* 144 */

typedef __attribute__((ext_vector_type(8))) short bf16x8;
typedef __attribute__((ext_vector_type(4))) float f32x4;

__device__ __forceinline__ ushort f2bf(float f) {
    // round-to-nearest-even fp32 -> bf16 (finite inputs)
    unsigned u = __float_as_uint(f);
    unsigned r = (u + 0x7FFFu + ((u >> 16) & 1u)) >> 16;
    return (ushort)r;
}

// ---------------------------------------------------------------------------
// Embedding gather: res[l, d] = embed[ids[l], d]
// ---------------------------------------------------------------------------
__global__ __launch_bounds__(256) void embed_kernel(const int* __restrict__ ids,
                                                    const float* __restrict__ embed,
                                                    float* __restrict__ res) {
    int idx = blockIdx.x * 256 + threadIdx.x;
    if (idx >= LSEQ * D_MODEL) return;
    int l = idx / D_MODEL;
    int d = idx - l * D_MODEL;
    res[idx] = embed[(size_t)ids[l] * D_MODEL + d];
}

// ---------------------------------------------------------------------------
// (optional residual += hidden) then LayerNorm over D_MODEL. One block per row.
// Writes fp32 (out32) or bf16 bits (out16), whichever is non-null.
// ---------------------------------------------------------------------------
__global__ __launch_bounds__(256) void add_ln_kernel(float* __restrict__ res,
                                                     const float* __restrict__ hid,
                                                     const float* __restrict__ w,
                                                     const float* __restrict__ b,
                                                     float* __restrict__ out32,
                                                     ushort* __restrict__ out16,
                                                     int addFlag) {
    const int l = blockIdx.x;
    const int t = threadIdx.x;
    __shared__ float sbuf[8];
    float loc[7];
    float* row = res + (size_t)l * D_MODEL;

    float sum = 0.f;
#pragma unroll
    for (int i = 0; i < 7; ++i) {
        int d = t + i * 256;
        float v = row[d];
        if (addFlag) { v += hid[(size_t)l * D_MODEL + d]; row[d] = v; }
        loc[i] = v;
        sum += v;
    }
#pragma unroll
    for (int o = 32; o > 0; o >>= 1) sum += __shfl_down(sum, o, 64);
    if ((t & 63) == 0) sbuf[t >> 6] = sum;
    __syncthreads();
    if (t == 0) sbuf[4] = sbuf[0] + sbuf[1] + sbuf[2] + sbuf[3];
    __syncthreads();
    const float mu = sbuf[4] * (1.f / D_MODEL);

    float vs = 0.f;
#pragma unroll
    for (int i = 0; i < 7; ++i) { float d0 = loc[i] - mu; vs += d0 * d0; }
#pragma unroll
    for (int o = 32; o > 0; o >>= 1) vs += __shfl_down(vs, o, 64);
    __syncthreads();
    if ((t & 63) == 0) sbuf[t >> 6] = vs;
    __syncthreads();
    if (t == 0) sbuf[4] = sbuf[0] + sbuf[1] + sbuf[2] + sbuf[3];
    __syncthreads();
    const float rstd = rsqrtf(sbuf[4] * (1.f / D_MODEL) + 1e-5f);

#pragma unroll
    for (int i = 0; i < 7; ++i) {
        int d = t + i * 256;
        float v = (loc[i] - mu) * rstd * w[d] + b[d];
        if (out16) out16[(size_t)l * D_MODEL + d] = f2bf(v);
        else       out32[(size_t)l * D_MODEL + d] = v;
    }
}

// ---------------------------------------------------------------------------
// bf16 MFMA GEMM (NT): C[m,n] = sum_k A[m,k] * W[n,k]
// A: bf16 bits, M x lda row-major. W: fp32 N x K row-major (converted to bf16
// in-register after LDS staging). C: fp32 M x N.
// Block tile: BM x 128, BK=32. 4 waves, wave tile (BMF*16) x 64.
// Requires: M % BM == 0, N % 128 == 0, K % 32 == 0, lda % 8 == 0.
// ---------------------------------------------------------------------------
template<int BMF>  // fragments per wave in m: 4 -> BM=128, 2 -> BM=64
__global__ __launch_bounds__(256) void gemm_mfma(const ushort* __restrict__ A, int lda,
                                                 const float* __restrict__ W,
                                                 float* __restrict__ C,
                                                 int N, int K) {
    constexpr int BM = BMF * 32;
    constexpr int BK = 32;
    __shared__ ushort As[BM * BK];   // [m][k], 64 B rows
    __shared__ float  Bs[128 * BK];  // [n][k], 128 B rows

    const int tid  = threadIdx.x;
    const int lane = tid & 63;
    const int wave = tid >> 6;
    const int m0 = blockIdx.y * BM;
    const int n0 = blockIdx.x * 128;
    const int wm = (wave >> 1) * (BMF * 16);
    const int wn = (wave & 1) * 64;
    const int frow = lane & 15;
    const int fkg  = lane >> 4;      // 0..3

    f32x4 acc[BMF][4] = {};

    for (int k0 = 0; k0 < K; k0 += BK) {
        // stage A tile: BM*32 bf16 = BM*64 B -> BM*4 chunks of 16 B
#pragma unroll
        for (int i = 0; i < BMF / 2; ++i) {
            int c = tid + i * 256;
            int row = c >> 2;            // 4 chunks (32 bf16) per row
            int kc  = (c & 3) * 8;
            __builtin_amdgcn_global_load_lds(
                (const __attribute__((address_space(1))) void*)(A + (size_t)(m0 + row) * lda + k0 + kc),
                (__attribute__((address_space(3))) void*)(As + c * 8), 16, 0, 0);
        }
        // stage B tile: 128*32 fp32 = 16 KB -> 1024 chunks of 16 B
#pragma unroll
        for (int i = 0; i < 4; ++i) {
            int c = tid + i * 256;
            int row = c >> 3;            // 8 chunks (32 fp32) per row
            int kc  = (c & 7) * 4;
            __builtin_amdgcn_global_load_lds(
                (const __attribute__((address_space(1))) void*)(W + (size_t)(n0 + row) * K + k0 + kc),
                (__attribute__((address_space(3))) void*)(Bs + c * 4), 16, 0, 0);
        }
        __syncthreads();

        bf16x8 af[BMF];
#pragma unroll
        for (int i = 0; i < BMF; ++i)
            af[i] = *(const bf16x8*)(As + (wm + i * 16 + frow) * BK + fkg * 8);

#pragma unroll
        for (int j = 0; j < 4; ++j) {
            const float* bp = Bs + (wn + j * 16 + frow) * BK + fkg * 8;
            f32x4 lo = *(const f32x4*)bp;
            f32x4 hi = *(const f32x4*)(bp + 4);
            bf16x8 bb;
            bb[0] = (short)f2bf(lo[0]); bb[1] = (short)f2bf(lo[1]);
            bb[2] = (short)f2bf(lo[2]); bb[3] = (short)f2bf(lo[3]);
            bb[4] = (short)f2bf(hi[0]); bb[5] = (short)f2bf(hi[1]);
            bb[6] = (short)f2bf(hi[2]); bb[7] = (short)f2bf(hi[3]);
#pragma unroll
            for (int i = 0; i < BMF; ++i)
                acc[i][j] = __builtin_amdgcn_mfma_f32_16x16x32_bf16(af[i], bb, acc[i][j], 0, 0, 0);
        }
        __syncthreads();
    }

    // epilogue: D row = fkg*4 + r, col = frow (verified m89/m91 mapping)
#pragma unroll
    for (int i = 0; i < BMF; ++i) {
#pragma unroll
        for (int r = 0; r < 4; ++r) {
            int m = m0 + wm + i * 16 + fkg * 4 + r;
            float* cp = C + (size_t)m * N + n0 + wn + frow;
#pragma unroll
            for (int j = 0; j < 4; ++j)
                cp[j * 16] = acc[i][j][r];
        }
    }
}

// ---------------------------------------------------------------------------
// Tiled fp32 GEMM (NT) for the small projections (x_proj, dt_proj).
// ---------------------------------------------------------------------------
#define GTILE 64
#define GKT   16
__global__ __launch_bounds__(256) void gemm_nt(const float* __restrict__ A, int lda,
                                               const float* __restrict__ W,
                                               float* __restrict__ C,
                                               int M, int N, int K,
                                               const float* __restrict__ bias, int act) {
    __shared__ float As[GTILE][GKT + 1];
    __shared__ float Ws[GTILE][GKT + 1];
    const int tid = threadIdx.x;
    const int m0 = blockIdx.y * GTILE;
    const int n0 = blockIdx.x * GTILE;
    const int ty = tid >> 4;
    const int tx = tid & 15;
    const int lrow = tid >> 2;
    const int lk4 = (tid & 3) * 4;

    float acc[4][4] = {};

    for (int k0 = 0; k0 < K; k0 += GKT) {
        {
            const float4 v = *reinterpret_cast<const float4*>(
                A + (size_t)(m0 + lrow) * lda + k0 + lk4);
            As[lrow][lk4 + 0] = v.x; As[lrow][lk4 + 1] = v.y;
            As[lrow][lk4 + 2] = v.z; As[lrow][lk4 + 3] = v.w;
        }
        {
            const int n = n0 + lrow;
            float4 v = make_float4(0.f, 0.f, 0.f, 0.f);
            if (n < N)
                v = *reinterpret_cast<const float4*>(W + (size_t)n * K + k0 + lk4);
            Ws[lrow][lk4 + 0] = v.x; Ws[lrow][lk4 + 1] = v.y;
            Ws[lrow][lk4 + 2] = v.z; Ws[lrow][lk4 + 3] = v.w;
        }
        __syncthreads();
#pragma unroll
        for (int k = 0; k < GKT; ++k) {
            float a[4], bb[4];
#pragma unroll
            for (int i = 0; i < 4; ++i) a[i] = As[ty * 4 + i][k];
#pragma unroll
            for (int j = 0; j < 4; ++j) bb[j] = Ws[tx * 4 + j][k];
#pragma unroll
            for (int i = 0; i < 4; ++i)
#pragma unroll
                for (int j = 0; j < 4; ++j) acc[i][j] = fmaf(a[i], bb[j], acc[i][j]);
        }
        __syncthreads();
    }

#pragma unroll
    for (int i = 0; i < 4; ++i) {
        const int m = m0 + ty * 4 + i;
#pragma unroll
        for (int j = 0; j < 4; ++j) {
            const int n = n0 + tx * 4 + j;
            if (n < N) {
                float v = acc[i][j];
                if (bias) v += bias[n];
                if (act == 1) v = (v > 20.f) ? v : __logf(1.f + __expf(v));
                C[(size_t)m * N + n] = v;
            }
        }
    }
}

// ---------------------------------------------------------------------------
// Causal depthwise conv (k=4, left pad 3) + bias + SiLU.
// ---------------------------------------------------------------------------
__global__ __launch_bounds__(256) void conv_silu_kernel(const float* __restrict__ xz,
                                                        const float* __restrict__ cw,
                                                        const float* __restrict__ cb,
                                                        float* __restrict__ xc) {
    int idx = blockIdx.x * 256 + threadIdx.x;
    if (idx >= LSEQ * D_INNER) return;
    int l = idx / D_INNER;
    int c = idx - l * D_INNER;
    const float4 w = *reinterpret_cast<const float4*>(cw + (size_t)c * D_CONV);
    float s = cb[c];
    const float wk[4] = {w.x, w.y, w.z, w.w};
#pragma unroll
    for (int k = 0; k < D_CONV; ++k) {
        int ll = l - (D_CONV - 1) + k;
        if (ll >= 0) s = fmaf(wk[k], xz[(size_t)ll * (2 * D_INNER) + c], s);
    }
    const float sig = 1.f / (1.f + __expf(-s));
    xc[idx] = s * sig;
}

// ---------------------------------------------------------------------------
// Selective scan. One thread per channel d, 16 states in registers.
// Batch-8 load prefetch to cover memory latency (1 wave/CU here).
// Writes y (D-skip + z-gate applied) as bf16 bits for the out_proj MFMA GEMM.
// ---------------------------------------------------------------------------
__global__ __launch_bounds__(64) void scan_kernel(const float* __restrict__ dt,
                                                  const float* __restrict__ xc,
                                                  const float* __restrict__ dbl,
                                                  const float* __restrict__ A_log,
                                                  const float* __restrict__ Dp,
                                                  const float* __restrict__ xz,
                                                  ushort* __restrict__ ybf) {
    const int d = blockIdx.x * 64 + threadIdx.x;
    __shared__ float Bs[32][D_STATE];
    __shared__ float Cs[32][D_STATE];
    float h[D_STATE], A2[D_STATE];
#pragma unroll
    for (int s = 0; s < D_STATE; ++s) {
        h[s] = 0.f;
        A2[s] = -__expf(A_log[(size_t)d * D_STATE + s]) * 1.4426950408889634f;
    }
    const float Dd = Dp[d];

    for (int l0 = 0; l0 < LSEQ; l0 += 32) {
        __syncthreads();
        for (int t = threadIdx.x; t < 32 * D_STATE; t += 64) {
            int ll = t >> 4, s = t & 15;
            Bs[ll][s] = dbl[(size_t)(l0 + ll) * XPROJ_N + DT_RANK + s];
            Cs[ll][s] = dbl[(size_t)(l0 + ll) * XPROJ_N + DT_RANK + D_STATE + s];
        }
        __syncthreads();
        for (int li0 = 0; li0 < 32; li0 += 8) {
            float dtv8[8], xcv8[8], zv8[8];
#pragma unroll
            for (int q = 0; q < 8; ++q) {
                const int l = l0 + li0 + q;
                dtv8[q] = dt[(size_t)l * D_INNER + d];
                xcv8[q] = xc[(size_t)l * D_INNER + d];
                zv8[q]  = xz[(size_t)l * (2 * D_INNER) + D_INNER + d];
            }
#pragma unroll
            for (int q = 0; q < 8; ++q) {
                const int li = li0 + q;
                const float dtv = dtv8[q];
                const float xcv = xcv8[q];
                const float coef = dtv * xcv;
                float a0 = 0.f, a1 = 0.f, a2 = 0.f, a3 = 0.f;
#pragma unroll
                for (int s = 0; s < D_STATE; s += 4) {
                    float e0 = exp2f(dtv * A2[s + 0]);
                    float e1 = exp2f(dtv * A2[s + 1]);
                    float e2 = exp2f(dtv * A2[s + 2]);
                    float e3 = exp2f(dtv * A2[s + 3]);
                    h[s + 0] = fmaf(e0, h[s + 0], coef * Bs[li][s + 0]);
                    h[s + 1] = fmaf(e1, h[s + 1], coef * Bs[li][s + 1]);
                    h[s + 2] = fmaf(e2, h[s + 2], coef * Bs[li][s + 2]);
                    h[s + 3] = fmaf(e3, h[s + 3], coef * Bs[li][s + 3]);
                    a0 = fmaf(h[s + 0], Cs[li][s + 0], a0);
                    a1 = fmaf(h[s + 1], Cs[li][s + 1], a1);
                    a2 = fmaf(h[s + 2], Cs[li][s + 2], a2);
                    a3 = fmaf(h[s + 3], Cs[li][s + 3], a3);
                }
                const float zv = zv8[q];
                const float sig = 1.f / (1.f + __expf(-zv));
                const float y = ((a0 + a1) + (a2 + a3) + Dd * xcv) * (zv * sig);
                ybf[(size_t)(l0 + li) * D_INNER + d] = f2bf(y);
            }
        }
    }
}

// ---------------------------------------------------------------------------
extern "C" void kernel_launch(void* const* d_in, const int* in_sizes, int n_in,
                              void* d_out, int out_size, void* d_ws, size_t ws_size,
                              hipStream_t stream) {
    const int*   ids       = (const int*)d_in[0];
    const float* embed     = (const float*)d_in[1];
    const float* in_proj_w = (const float*)d_in[2];
    const float* conv_w    = (const float*)d_in[3];
    const float* conv_b    = (const float*)d_in[4];
    const float* x_proj_w  = (const float*)d_in[5];
    const float* dt_proj_w = (const float*)d_in[6];
    const float* dt_proj_b = (const float*)d_in[7];
    const float* A_log     = (const float*)d_in[8];
    const float* D_skip    = (const float*)d_in[9];
    const float* out_proj_w= (const float*)d_in[10];
    const float* norm_w    = (const float*)d_in[11];
    const float* norm_b    = (const float*)d_in[12];
    const float* fin_w     = (const float*)d_in[13];
    const float* fin_b     = (const float*)d_in[14];
    float* out = (float*)d_out;

    float* ws = (float*)d_ws;
    float* res    = ws; ws += LSEQ * D_MODEL;
    float* hidden = ws; ws += LSEQ * D_MODEL;
    float* xz     = ws; ws += (size_t)LSEQ * 2 * D_INNER;
    float* xc     = ws; ws += (size_t)LSEQ * D_INNER;
    float* dbl    = ws; ws += LSEQ * XPROJ_N;
    float* dty    = ws; ws += (size_t)LSEQ * D_INNER;
    ushort* hbf   = (ushort*)ws; ws += (LSEQ * D_MODEL + 1) / 2;
    ushort* ybf   = (ushort*)ws;

    embed_kernel<<<(LSEQ * D_MODEL + 255) / 256, 256, 0, stream>>>(ids, embed, res);

    for (int i = 0; i < NLAYER; ++i) {
        add_ln_kernel<<<LSEQ, 256, 0, stream>>>(
            res, hidden, norm_w + (size_t)i * D_MODEL, norm_b + (size_t)i * D_MODEL,
            nullptr, hbf, i > 0 ? 1 : 0);

        // in_proj: [512 x 1792] x [7168 x 1792]^T -> xz [512 x 7168]
        gemm_mfma<4><<<dim3(2 * D_INNER / 128, LSEQ / 128), 256, 0, stream>>>(
            hbf, D_MODEL, in_proj_w + (size_t)i * 2 * D_INNER * D_MODEL, xz,
            2 * D_INNER, D_MODEL);

        conv_silu_kernel<<<(LSEQ * D_INNER + 255) / 256, 256, 0, stream>>>(
            xz, conv_w + (size_t)i * D_INNER * D_CONV, conv_b + (size_t)i * D_INNER, xc);

        gemm_nt<<<dim3((XPROJ_N + GTILE - 1) / GTILE, LSEQ / GTILE), 256, 0, stream>>>(
            xc, D_INNER, x_proj_w + (size_t)i * XPROJ_N * D_INNER, dbl,
            LSEQ, XPROJ_N, D_INNER, nullptr, 0);

        gemm_nt<<<dim3((D_INNER + GTILE - 1) / GTILE, LSEQ / GTILE), 256, 0, stream>>>(
            dbl, XPROJ_N, dt_proj_w + (size_t)i * D_INNER * DT_RANK, dty,
            LSEQ, D_INNER, DT_RANK, dt_proj_b + (size_t)i * D_INNER, 1);

        scan_kernel<<<D_INNER / 64, 64, 0, stream>>>(
            dty, xc, dbl, A_log + (size_t)i * D_INNER * D_STATE,
            D_skip + (size_t)i * D_INNER, xz, ybf);

        // out_proj: [512 x 3584] x [1792 x 3584]^T -> hidden [512 x 1792]
        gemm_mfma<2><<<dim3(D_MODEL / 128, LSEQ / 64), 256, 0, stream>>>(
            ybf, D_INNER, out_proj_w + (size_t)i * D_MODEL * D_INNER, hidden,
            D_MODEL, D_INNER);
    }

    add_ln_kernel<<<LSEQ, 256, 0, stream>>>(res, hidden, fin_w, fin_b, out, nullptr, 1);
}

// Round 3
// 2508.409 us; speedup vs baseline: 2.2679x; 1.4868x over previous
//
#include <hip/hip_runtime.h>
#include <hip/hip_bf16.h>
#include <math.h>

#define D_MODEL 1792
#define D_INNER 3584
#define D_STATE 16
#define D_CONV  4
#define DT_RANK 112
#define NLAYER  4
#define LSEQ    512
#define XPROJ_N (DT_RANK + 2 * D_STATE) /* 144 */
#define KSPLIT  8                        /* x_proj split-K factor */
#define KCHUNK  (D_INNER / KSPLIT)       /* 448 */

typedef __attribute__((ext_vector_type(8))) short bf16x8;
typedef __attribute__((ext_vector_type(4))) float f32x4;

__device__ __forceinline__ ushort f2bf(float f) {
    // round-to-nearest-even fp32 -> bf16 (finite inputs)
    unsigned u = __float_as_uint(f);
    unsigned r = (u + 0x7FFFu + ((u >> 16) & 1u)) >> 16;
    return (ushort)r;
}

// ---------------------------------------------------------------------------
// Embedding gather
// ---------------------------------------------------------------------------
__global__ __launch_bounds__(256) void embed_kernel(const int* __restrict__ ids,
                                                    const float* __restrict__ embed,
                                                    float* __restrict__ res) {
    int idx = blockIdx.x * 256 + threadIdx.x;
    if (idx >= LSEQ * D_MODEL) return;
    int l = idx / D_MODEL;
    int d = idx - l * D_MODEL;
    res[idx] = embed[(size_t)ids[l] * D_MODEL + d];
}

// ---------------------------------------------------------------------------
// (optional residual += hidden) then LayerNorm. One block per row.
// ---------------------------------------------------------------------------
__global__ __launch_bounds__(256) void add_ln_kernel(float* __restrict__ res,
                                                     const float* __restrict__ hid,
                                                     const float* __restrict__ w,
                                                     const float* __restrict__ b,
                                                     float* __restrict__ out32,
                                                     ushort* __restrict__ out16,
                                                     int addFlag) {
    const int l = blockIdx.x;
    const int t = threadIdx.x;
    __shared__ float sbuf[8];
    float loc[7];
    float* row = res + (size_t)l * D_MODEL;

    float sum = 0.f;
#pragma unroll
    for (int i = 0; i < 7; ++i) {
        int d = t + i * 256;
        float v = row[d];
        if (addFlag) { v += hid[(size_t)l * D_MODEL + d]; row[d] = v; }
        loc[i] = v;
        sum += v;
    }
#pragma unroll
    for (int o = 32; o > 0; o >>= 1) sum += __shfl_down(sum, o, 64);
    if ((t & 63) == 0) sbuf[t >> 6] = sum;
    __syncthreads();
    if (t == 0) sbuf[4] = sbuf[0] + sbuf[1] + sbuf[2] + sbuf[3];
    __syncthreads();
    const float mu = sbuf[4] * (1.f / D_MODEL);

    float vs = 0.f;
#pragma unroll
    for (int i = 0; i < 7; ++i) { float d0 = loc[i] - mu; vs += d0 * d0; }
#pragma unroll
    for (int o = 32; o > 0; o >>= 1) vs += __shfl_down(vs, o, 64);
    __syncthreads();
    if ((t & 63) == 0) sbuf[t >> 6] = vs;
    __syncthreads();
    if (t == 0) sbuf[4] = sbuf[0] + sbuf[1] + sbuf[2] + sbuf[3];
    __syncthreads();
    const float rstd = rsqrtf(sbuf[4] * (1.f / D_MODEL) + 1e-5f);

#pragma unroll
    for (int i = 0; i < 7; ++i) {
        int d = t + i * 256;
        float v = (loc[i] - mu) * rstd * w[d] + b[d];
        if (out16) out16[(size_t)l * D_MODEL + d] = f2bf(v);
        else       out32[(size_t)l * D_MODEL + d] = v;
    }
}

// ---------------------------------------------------------------------------
// bf16 MFMA GEMM (NT): C[m,n] = sum_k A[m,k] * W[n,k]
// A: bf16 bits, row-major with leading dim lda. W: fp32 (WBF=0, converted
// in-register after LDS staging) or bf16 bits (WBF=1). C: fp32.
// Block: BM x 128, BK=32, 4 waves, wave tile (BMF*16) x 64.
// ACT=1: out = softplus(out + bias[n]).
// Requires: M % BM == 0, N % 128 == 0, K % 32 == 0.
// ---------------------------------------------------------------------------
template<int BMF, int WBF, int ACT>
__global__ __launch_bounds__(256) void gemm_mfma(const ushort* __restrict__ A, int lda,
                                                 const void* __restrict__ Wv,
                                                 float* __restrict__ C,
                                                 int N, int K,
                                                 const float* __restrict__ bias) {
    constexpr int BM = BMF * 32;
    constexpr int BK = 32;
    __shared__ ushort As[BM * BK];
    __shared__ __attribute__((aligned(16))) char Bs[WBF ? (128 * BK * 2) : (128 * BK * 4)];

    const int tid  = threadIdx.x;
    const int lane = tid & 63;
    const int wave = tid >> 6;
    const int m0 = blockIdx.y * BM;
    const int n0 = blockIdx.x * 128;
    const int wm = (wave >> 1) * (BMF * 16);
    const int wn = (wave & 1) * 64;
    const int frow = lane & 15;
    const int fkg  = lane >> 4;

    f32x4 acc[BMF][4] = {};

    for (int k0 = 0; k0 < K; k0 += BK) {
        // stage A: BM*32 bf16 -> BM*4 chunks of 16 B
#pragma unroll
        for (int i = 0; i < BMF / 2; ++i) {
            int c = tid + i * 256;
            int row = c >> 2;
            int kc  = (c & 3) * 8;
            __builtin_amdgcn_global_load_lds(
                (const __attribute__((address_space(1))) void*)(A + (size_t)(m0 + row) * lda + k0 + kc),
                (__attribute__((address_space(3))) void*)(As + c * 8), 16, 0, 0);
        }
        // stage B
        if (WBF) {
            const ushort* W = (const ushort*)Wv;
#pragma unroll
            for (int i = 0; i < 2; ++i) {
                int c = tid + i * 256;
                int row = c >> 2;
                int kc  = (c & 3) * 8;
                __builtin_amdgcn_global_load_lds(
                    (const __attribute__((address_space(1))) void*)(W + (size_t)(n0 + row) * K + k0 + kc),
                    (__attribute__((address_space(3))) void*)(Bs + c * 16), 16, 0, 0);
            }
        } else {
            const float* W = (const float*)Wv;
#pragma unroll
            for (int i = 0; i < 4; ++i) {
                int c = tid + i * 256;
                int row = c >> 3;
                int kc  = (c & 7) * 4;
                __builtin_amdgcn_global_load_lds(
                    (const __attribute__((address_space(1))) void*)(W + (size_t)(n0 + row) * K + k0 + kc),
                    (__attribute__((address_space(3))) void*)(Bs + c * 16), 16, 0, 0);
            }
        }
        __syncthreads();

        bf16x8 af[BMF];
#pragma unroll
        for (int i = 0; i < BMF; ++i)
            af[i] = *(const bf16x8*)(As + (wm + i * 16 + frow) * BK + fkg * 8);

#pragma unroll
        for (int j = 0; j < 4; ++j) {
            bf16x8 bb;
            if (WBF) {
                bb = *(const bf16x8*)((const ushort*)Bs + (wn + j * 16 + frow) * BK + fkg * 8);
            } else {
                const float* bp = (const float*)Bs + (wn + j * 16 + frow) * BK + fkg * 8;
                f32x4 lo = *(const f32x4*)bp;
                f32x4 hi = *(const f32x4*)(bp + 4);
                bb[0] = (short)f2bf(lo[0]); bb[1] = (short)f2bf(lo[1]);
                bb[2] = (short)f2bf(lo[2]); bb[3] = (short)f2bf(lo[3]);
                bb[4] = (short)f2bf(hi[0]); bb[5] = (short)f2bf(hi[1]);
                bb[6] = (short)f2bf(hi[2]); bb[7] = (short)f2bf(hi[3]);
            }
#pragma unroll
            for (int i = 0; i < BMF; ++i)
                acc[i][j] = __builtin_amdgcn_mfma_f32_16x16x32_bf16(af[i], bb, acc[i][j], 0, 0, 0);
        }
        __syncthreads();
    }

    float bj[4];
    if (ACT) {
#pragma unroll
        for (int j = 0; j < 4; ++j) bj[j] = bias[n0 + wn + frow + j * 16];
    }

#pragma unroll
    for (int i = 0; i < BMF; ++i) {
#pragma unroll
        for (int r = 0; r < 4; ++r) {
            int m = m0 + wm + i * 16 + fkg * 4 + r;
            float* cp = C + (size_t)m * N + n0 + wn + frow;
#pragma unroll
            for (int j = 0; j < 4; ++j) {
                float v = acc[i][j][r];
                if (ACT) {
                    v += bj[j];
                    v = (v > 20.f) ? v : __logf(1.f + __expf(v));
                }
                cp[j * 16] = v;
            }
        }
    }
}

// ---------------------------------------------------------------------------
// x_proj split-K MFMA: dbl_part[z][m][n] = sum_{k in chunk z} xc[m,k]*W[n,k]
// Grid: (9 n-tiles of 16, 8 m-tiles of 64, KSPLIT). 4 waves, 16x16 tile each.
// ---------------------------------------------------------------------------
__global__ __launch_bounds__(256) void xproj_split(const ushort* __restrict__ xcbf,
                                                   const float* __restrict__ W,
                                                   float* __restrict__ xpart) {
    __shared__ ushort As[64 * 32];
    __shared__ float  Ws[16 * 32];
    const int tid  = threadIdx.x;
    const int lane = tid & 63;
    const int wave = tid >> 6;
    const int n0 = blockIdx.x * 16;
    const int m0 = blockIdx.y * 64;
    const int z  = blockIdx.z;
    const int wm = wave * 16;
    const int frow = lane & 15;
    const int fkg  = lane >> 4;
    const int kbase = z * KCHUNK;

    f32x4 acc = {};

    for (int it = 0; it < KCHUNK / 32; ++it) {
        const int k0 = kbase + it * 32;
        {   // A: 64 rows x 32 bf16 = 256 chunks of 16 B
            int row = tid >> 2;
            int kc  = (tid & 3) * 8;
            __builtin_amdgcn_global_load_lds(
                (const __attribute__((address_space(1))) void*)(xcbf + (size_t)(m0 + row) * D_INNER + k0 + kc),
                (__attribute__((address_space(3))) void*)(As + tid * 8), 16, 0, 0);
        }
        if (tid < 128) {  // W: 16 rows x 32 fp32 = 128 chunks of 16 B
            int row = tid >> 3;
            int kc  = (tid & 7) * 4;
            __builtin_amdgcn_global_load_lds(
                (const __attribute__((address_space(1))) void*)(W + (size_t)(n0 + row) * D_INNER + k0 + kc),
                (__attribute__((address_space(3))) void*)(Ws + tid * 4), 16, 0, 0);
        }
        __syncthreads();

        bf16x8 af = *(const bf16x8*)(As + (wm + frow) * 32 + fkg * 8);
        const float* bp = Ws + frow * 32 + fkg * 8;
        f32x4 lo = *(const f32x4*)bp;
        f32x4 hi = *(const f32x4*)(bp + 4);
        bf16x8 bb;
        bb[0] = (short)f2bf(lo[0]); bb[1] = (short)f2bf(lo[1]);
        bb[2] = (short)f2bf(lo[2]); bb[3] = (short)f2bf(lo[3]);
        bb[4] = (short)f2bf(hi[0]); bb[5] = (short)f2bf(hi[1]);
        bb[6] = (short)f2bf(hi[2]); bb[7] = (short)f2bf(hi[3]);
        acc = __builtin_amdgcn_mfma_f32_16x16x32_bf16(af, bb, acc, 0, 0, 0);
        __syncthreads();
    }

#pragma unroll
    for (int r = 0; r < 4; ++r) {
        int m = m0 + wm + fkg * 4 + r;
        int n = n0 + frow;
        xpart[((size_t)z * LSEQ + m) * XPROJ_N + n] = acc[r];
    }
}

// ---------------------------------------------------------------------------
// Reduce split-K partials -> dbl fp32; also emit zero-padded bf16 dt matrix
// (512 x 128, cols 0..111 = dbl cols 0..111, cols 112..127 = 0).
// ---------------------------------------------------------------------------
__global__ __launch_bounds__(256) void xreduce_kernel(const float* __restrict__ xpart,
                                                      float* __restrict__ dbl,
                                                      ushort* __restrict__ dtb) {
    int idx = blockIdx.x * 256 + threadIdx.x;
    if (idx >= LSEQ * XPROJ_N) return;
    int m = idx / XPROJ_N;
    int n = idx - m * XPROJ_N;
    float s = 0.f;
#pragma unroll
    for (int z = 0; z < KSPLIT; ++z)
        s += xpart[(size_t)z * LSEQ * XPROJ_N + idx];
    dbl[idx] = s;
    if (n < DT_RANK)      dtb[m * 128 + n] = f2bf(s);
    else if (n < 128)     dtb[m * 128 + n] = 0;
}

// ---------------------------------------------------------------------------
// Convert one layer's dt_proj_w (3584 x 112 fp32) -> zero-padded bf16 3584x128
// ---------------------------------------------------------------------------
__global__ __launch_bounds__(256) void dtw_cvt_kernel(const float* __restrict__ w,
                                                      ushort* __restrict__ o) {
    int idx = blockIdx.x * 256 + threadIdx.x;
    if (idx >= D_INNER * 128) return;
    int r = idx >> 7, c = idx & 127;
    o[idx] = (c < DT_RANK) ? f2bf(w[(size_t)r * DT_RANK + c]) : (ushort)0;
}

// ---------------------------------------------------------------------------
// Causal depthwise conv (k=4) + bias + SiLU. Emits fp32 (scan) + bf16 (x_proj).
// ---------------------------------------------------------------------------
__global__ __launch_bounds__(256) void conv_silu_kernel(const float* __restrict__ xz,
                                                        const float* __restrict__ cw,
                                                        const float* __restrict__ cb,
                                                        float* __restrict__ xc,
                                                        ushort* __restrict__ xcbf) {
    int idx = blockIdx.x * 256 + threadIdx.x;
    if (idx >= LSEQ * D_INNER) return;
    int l = idx / D_INNER;
    int c = idx - l * D_INNER;
    const float4 w = *reinterpret_cast<const float4*>(cw + (size_t)c * D_CONV);
    float s = cb[c];
    const float wk[4] = {w.x, w.y, w.z, w.w};
#pragma unroll
    for (int k = 0; k < D_CONV; ++k) {
        int ll = l - (D_CONV - 1) + k;
        if (ll >= 0) s = fmaf(wk[k], xz[(size_t)ll * (2 * D_INNER) + c], s);
    }
    const float sig = 1.f / (1.f + __expf(-s));
    const float v = s * sig;
    xc[idx] = v;
    xcbf[idx] = f2bf(v);
}

// ---------------------------------------------------------------------------
// Selective scan. One thread per channel d, 16 states in registers.
// ---------------------------------------------------------------------------
__global__ __launch_bounds__(64) void scan_kernel(const float* __restrict__ dt,
                                                  const float* __restrict__ xc,
                                                  const float* __restrict__ dbl,
                                                  const float* __restrict__ A_log,
                                                  const float* __restrict__ Dp,
                                                  const float* __restrict__ xz,
                                                  ushort* __restrict__ ybf) {
    const int d = blockIdx.x * 64 + threadIdx.x;
    __shared__ float Bs[32][D_STATE];
    __shared__ float Cs[32][D_STATE];
    float h[D_STATE], A2[D_STATE];
#pragma unroll
    for (int s = 0; s < D_STATE; ++s) {
        h[s] = 0.f;
        A2[s] = -__expf(A_log[(size_t)d * D_STATE + s]) * 1.4426950408889634f;
    }
    const float Dd = Dp[d];

    for (int l0 = 0; l0 < LSEQ; l0 += 32) {
        __syncthreads();
        for (int t = threadIdx.x; t < 32 * D_STATE; t += 64) {
            int ll = t >> 4, s = t & 15;
            Bs[ll][s] = dbl[(size_t)(l0 + ll) * XPROJ_N + DT_RANK + s];
            Cs[ll][s] = dbl[(size_t)(l0 + ll) * XPROJ_N + DT_RANK + D_STATE + s];
        }
        __syncthreads();
        for (int li0 = 0; li0 < 32; li0 += 8) {
            float dtv8[8], xcv8[8], zv8[8];
#pragma unroll
            for (int q = 0; q < 8; ++q) {
                const int l = l0 + li0 + q;
                dtv8[q] = dt[(size_t)l * D_INNER + d];
                xcv8[q] = xc[(size_t)l * D_INNER + d];
                zv8[q]  = xz[(size_t)l * (2 * D_INNER) + D_INNER + d];
            }
#pragma unroll
            for (int q = 0; q < 8; ++q) {
                const int li = li0 + q;
                const float dtv = dtv8[q];
                const float xcv = xcv8[q];
                const float coef = dtv * xcv;
                float a0 = 0.f, a1 = 0.f, a2 = 0.f, a3 = 0.f;
#pragma unroll
                for (int s = 0; s < D_STATE; s += 4) {
                    float e0 = exp2f(dtv * A2[s + 0]);
                    float e1 = exp2f(dtv * A2[s + 1]);
                    float e2 = exp2f(dtv * A2[s + 2]);
                    float e3 = exp2f(dtv * A2[s + 3]);
                    h[s + 0] = fmaf(e0, h[s + 0], coef * Bs[li][s + 0]);
                    h[s + 1] = fmaf(e1, h[s + 1], coef * Bs[li][s + 1]);
                    h[s + 2] = fmaf(e2, h[s + 2], coef * Bs[li][s + 2]);
                    h[s + 3] = fmaf(e3, h[s + 3], coef * Bs[li][s + 3]);
                    a0 = fmaf(h[s + 0], Cs[li][s + 0], a0);
                    a1 = fmaf(h[s + 1], Cs[li][s + 1], a1);
                    a2 = fmaf(h[s + 2], Cs[li][s + 2], a2);
                    a3 = fmaf(h[s + 3], Cs[li][s + 3], a3);
                }
                const float zv = zv8[q];
                const float sig = 1.f / (1.f + __expf(-zv));
                const float y = ((a0 + a1) + (a2 + a3) + Dd * xcv) * (zv * sig);
                ybf[(size_t)(l0 + li) * D_INNER + d] = f2bf(y);
            }
        }
    }
}

// ---------------------------------------------------------------------------
extern "C" void kernel_launch(void* const* d_in, const int* in_sizes, int n_in,
                              void* d_out, int out_size, void* d_ws, size_t ws_size,
                              hipStream_t stream) {
    const int*   ids       = (const int*)d_in[0];
    const float* embed     = (const float*)d_in[1];
    const float* in_proj_w = (const float*)d_in[2];
    const float* conv_w    = (const float*)d_in[3];
    const float* conv_b    = (const float*)d_in[4];
    const float* x_proj_w  = (const float*)d_in[5];
    const float* dt_proj_w = (const float*)d_in[6];
    const float* dt_proj_b = (const float*)d_in[7];
    const float* A_log     = (const float*)d_in[8];
    const float* D_skip    = (const float*)d_in[9];
    const float* out_proj_w= (const float*)d_in[10];
    const float* norm_w    = (const float*)d_in[11];
    const float* norm_b    = (const float*)d_in[12];
    const float* fin_w     = (const float*)d_in[13];
    const float* fin_b     = (const float*)d_in[14];
    float* out = (float*)d_out;

    float* ws = (float*)d_ws;
    float* res    = ws; ws += LSEQ * D_MODEL;
    float* hidden = ws; ws += LSEQ * D_MODEL;
    float* xz     = ws; ws += (size_t)LSEQ * 2 * D_INNER;
    float* xc     = ws; ws += (size_t)LSEQ * D_INNER;
    float* dbl    = ws; ws += LSEQ * XPROJ_N;
    float* dty    = ws; ws += (size_t)LSEQ * D_INNER;
    float* xpart  = ws; ws += (size_t)KSPLIT * LSEQ * XPROJ_N;
    ushort* hbf   = (ushort*)ws; ws += (LSEQ * D_MODEL) / 2;
    ushort* ybf   = (ushort*)ws; ws += (LSEQ * D_INNER) / 2;
    ushort* xcbf  = (ushort*)ws; ws += (LSEQ * D_INNER) / 2;
    ushort* dtb   = (ushort*)ws; ws += (LSEQ * 128) / 2;
    ushort* dtwbf = (ushort*)ws;

    embed_kernel<<<(LSEQ * D_MODEL + 255) / 256, 256, 0, stream>>>(ids, embed, res);

    for (int i = 0; i < NLAYER; ++i) {
        add_ln_kernel<<<LSEQ, 256, 0, stream>>>(
            res, hidden, norm_w + (size_t)i * D_MODEL, norm_b + (size_t)i * D_MODEL,
            nullptr, hbf, i > 0 ? 1 : 0);

        // in_proj: [512 x 1792] x [7168 x 1792]^T -> xz
        gemm_mfma<4, 0, 0><<<dim3(2 * D_INNER / 128, LSEQ / 128), 256, 0, stream>>>(
            hbf, D_MODEL, in_proj_w + (size_t)i * 2 * D_INNER * D_MODEL, xz,
            2 * D_INNER, D_MODEL, nullptr);

        conv_silu_kernel<<<(LSEQ * D_INNER + 255) / 256, 256, 0, stream>>>(
            xz, conv_w + (size_t)i * D_INNER * D_CONV, conv_b + (size_t)i * D_INNER,
            xc, xcbf);

        // x_proj split-K MFMA + reduce
        xproj_split<<<dim3(XPROJ_N / 16, LSEQ / 64, KSPLIT), 256, 0, stream>>>(
            xcbf, x_proj_w + (size_t)i * XPROJ_N * D_INNER, xpart);
        xreduce_kernel<<<(LSEQ * XPROJ_N + 255) / 256, 256, 0, stream>>>(xpart, dbl, dtb);

        // dt_proj: pad weights to K=128 bf16, then MFMA with softplus epilogue
        dtw_cvt_kernel<<<(D_INNER * 128 + 255) / 256, 256, 0, stream>>>(
            dt_proj_w + (size_t)i * D_INNER * DT_RANK, dtwbf);
        gemm_mfma<2, 1, 1><<<dim3(D_INNER / 128, LSEQ / 64), 256, 0, stream>>>(
            dtb, 128, dtwbf, dty, D_INNER, 128, dt_proj_b + (size_t)i * D_INNER);

        scan_kernel<<<D_INNER / 64, 64, 0, stream>>>(
            dty, xc, dbl, A_log + (size_t)i * D_INNER * D_STATE,
            D_skip + (size_t)i * D_INNER, xz, ybf);

        // out_proj: [512 x 3584] x [1792 x 3584]^T -> hidden
        gemm_mfma<2, 0, 0><<<dim3(D_MODEL / 128, LSEQ / 64), 256, 0, stream>>>(
            ybf, D_INNER, out_proj_w + (size_t)i * D_MODEL * D_INNER, hidden,
            D_MODEL, D_INNER, nullptr);
    }

    add_ln_kernel<<<LSEQ, 256, 0, stream>>>(res, hidden, fin_w, fin_b, out, nullptr, 1);
}

// Round 4
// 1535.522 us; speedup vs baseline: 3.7048x; 1.6336x over previous
//
#include <hip/hip_runtime.h>
#include <hip/hip_bf16.h>
#include <math.h>

#define D_MODEL 1792
#define D_INNER 3584
#define D_STATE 16
#define D_CONV  4
#define DT_RANK 112
#define NLAYER  4
#define LSEQ    512
#define XPROJ_N (DT_RANK + 2 * D_STATE) /* 144 */
#define KSPLIT  8                        /* x_proj split-K factor */
#define KCHUNK  (D_INNER / KSPLIT)       /* 448 */
#define SCH     32                       /* scan chunks */
#define SCL     (LSEQ / SCH)             /* 16 steps per chunk */

typedef __attribute__((ext_vector_type(8))) short bf16x8;
typedef __attribute__((ext_vector_type(4))) float f32x4;

__device__ __forceinline__ ushort f2bf(float f) {
    unsigned u = __float_as_uint(f);
    unsigned r = (u + 0x7FFFu + ((u >> 16) & 1u)) >> 16;
    return (ushort)r;
}

// ---------------------------------------------------------------------------
// Embedding gather
// ---------------------------------------------------------------------------
__global__ __launch_bounds__(256) void embed_kernel(const int* __restrict__ ids,
                                                    const float* __restrict__ embed,
                                                    float* __restrict__ res) {
    int idx = blockIdx.x * 256 + threadIdx.x;
    if (idx >= LSEQ * D_MODEL) return;
    int l = idx / D_MODEL;
    int d = idx - l * D_MODEL;
    res[idx] = embed[(size_t)ids[l] * D_MODEL + d];
}

// ---------------------------------------------------------------------------
// (optional residual += hidden) then LayerNorm. One block per row.
// ---------------------------------------------------------------------------
__global__ __launch_bounds__(256) void add_ln_kernel(float* __restrict__ res,
                                                     const float* __restrict__ hid,
                                                     const float* __restrict__ w,
                                                     const float* __restrict__ b,
                                                     float* __restrict__ out32,
                                                     ushort* __restrict__ out16,
                                                     int addFlag) {
    const int l = blockIdx.x;
    const int t = threadIdx.x;
    __shared__ float sbuf[8];
    float loc[7];
    float* row = res + (size_t)l * D_MODEL;

    float sum = 0.f;
#pragma unroll
    for (int i = 0; i < 7; ++i) {
        int d = t + i * 256;
        float v = row[d];
        if (addFlag) { v += hid[(size_t)l * D_MODEL + d]; row[d] = v; }
        loc[i] = v;
        sum += v;
    }
#pragma unroll
    for (int o = 32; o > 0; o >>= 1) sum += __shfl_down(sum, o, 64);
    if ((t & 63) == 0) sbuf[t >> 6] = sum;
    __syncthreads();
    if (t == 0) sbuf[4] = sbuf[0] + sbuf[1] + sbuf[2] + sbuf[3];
    __syncthreads();
    const float mu = sbuf[4] * (1.f / D_MODEL);

    float vs = 0.f;
#pragma unroll
    for (int i = 0; i < 7; ++i) { float d0 = loc[i] - mu; vs += d0 * d0; }
#pragma unroll
    for (int o = 32; o > 0; o >>= 1) vs += __shfl_down(vs, o, 64);
    __syncthreads();
    if ((t & 63) == 0) sbuf[t >> 6] = vs;
    __syncthreads();
    if (t == 0) sbuf[4] = sbuf[0] + sbuf[1] + sbuf[2] + sbuf[3];
    __syncthreads();
    const float rstd = rsqrtf(sbuf[4] * (1.f / D_MODEL) + 1e-5f);

#pragma unroll
    for (int i = 0; i < 7; ++i) {
        int d = t + i * 256;
        float v = (loc[i] - mu) * rstd * w[d] + b[d];
        if (out16) out16[(size_t)l * D_MODEL + d] = f2bf(v);
        else       out32[(size_t)l * D_MODEL + d] = v;
    }
}

// ---------------------------------------------------------------------------
// bf16 MFMA GEMM (NT). See Round-3 version; unchanged.
// ---------------------------------------------------------------------------
template<int BMF, int WBF, int ACT>
__global__ __launch_bounds__(256) void gemm_mfma(const ushort* __restrict__ A, int lda,
                                                 const void* __restrict__ Wv,
                                                 float* __restrict__ C,
                                                 int N, int K,
                                                 const float* __restrict__ bias) {
    constexpr int BM = BMF * 32;
    constexpr int BK = 32;
    __shared__ ushort As[BM * BK];
    __shared__ __attribute__((aligned(16))) char Bs[WBF ? (128 * BK * 2) : (128 * BK * 4)];

    const int tid  = threadIdx.x;
    const int lane = tid & 63;
    const int wave = tid >> 6;
    const int m0 = blockIdx.y * BM;
    const int n0 = blockIdx.x * 128;
    const int wm = (wave >> 1) * (BMF * 16);
    const int wn = (wave & 1) * 64;
    const int frow = lane & 15;
    const int fkg  = lane >> 4;

    f32x4 acc[BMF][4] = {};

    for (int k0 = 0; k0 < K; k0 += BK) {
#pragma unroll
        for (int i = 0; i < BMF / 2; ++i) {
            int c = tid + i * 256;
            int row = c >> 2;
            int kc  = (c & 3) * 8;
            __builtin_amdgcn_global_load_lds(
                (const __attribute__((address_space(1))) void*)(A + (size_t)(m0 + row) * lda + k0 + kc),
                (__attribute__((address_space(3))) void*)(As + c * 8), 16, 0, 0);
        }
        if (WBF) {
            const ushort* W = (const ushort*)Wv;
#pragma unroll
            for (int i = 0; i < 2; ++i) {
                int c = tid + i * 256;
                int row = c >> 2;
                int kc  = (c & 3) * 8;
                __builtin_amdgcn_global_load_lds(
                    (const __attribute__((address_space(1))) void*)(W + (size_t)(n0 + row) * K + k0 + kc),
                    (__attribute__((address_space(3))) void*)(Bs + c * 16), 16, 0, 0);
            }
        } else {
            const float* W = (const float*)Wv;
#pragma unroll
            for (int i = 0; i < 4; ++i) {
                int c = tid + i * 256;
                int row = c >> 3;
                int kc  = (c & 7) * 4;
                __builtin_amdgcn_global_load_lds(
                    (const __attribute__((address_space(1))) void*)(W + (size_t)(n0 + row) * K + k0 + kc),
                    (__attribute__((address_space(3))) void*)(Bs + c * 16), 16, 0, 0);
            }
        }
        __syncthreads();

        bf16x8 af[BMF];
#pragma unroll
        for (int i = 0; i < BMF; ++i)
            af[i] = *(const bf16x8*)(As + (wm + i * 16 + frow) * BK + fkg * 8);

#pragma unroll
        for (int j = 0; j < 4; ++j) {
            bf16x8 bb;
            if (WBF) {
                bb = *(const bf16x8*)((const ushort*)Bs + (wn + j * 16 + frow) * BK + fkg * 8);
            } else {
                const float* bp = (const float*)Bs + (wn + j * 16 + frow) * BK + fkg * 8;
                f32x4 lo = *(const f32x4*)bp;
                f32x4 hi = *(const f32x4*)(bp + 4);
                bb[0] = (short)f2bf(lo[0]); bb[1] = (short)f2bf(lo[1]);
                bb[2] = (short)f2bf(lo[2]); bb[3] = (short)f2bf(lo[3]);
                bb[4] = (short)f2bf(hi[0]); bb[5] = (short)f2bf(hi[1]);
                bb[6] = (short)f2bf(hi[2]); bb[7] = (short)f2bf(hi[3]);
            }
#pragma unroll
            for (int i = 0; i < BMF; ++i)
                acc[i][j] = __builtin_amdgcn_mfma_f32_16x16x32_bf16(af[i], bb, acc[i][j], 0, 0, 0);
        }
        __syncthreads();
    }

    float bj[4];
    if (ACT) {
#pragma unroll
        for (int j = 0; j < 4; ++j) bj[j] = bias[n0 + wn + frow + j * 16];
    }

#pragma unroll
    for (int i = 0; i < BMF; ++i) {
#pragma unroll
        for (int r = 0; r < 4; ++r) {
            int m = m0 + wm + i * 16 + fkg * 4 + r;
            float* cp = C + (size_t)m * N + n0 + wn + frow;
#pragma unroll
            for (int j = 0; j < 4; ++j) {
                float v = acc[i][j][r];
                if (ACT) {
                    v += bj[j];
                    v = (v > 20.f) ? v : __logf(1.f + __expf(v));
                }
                cp[j * 16] = v;
            }
        }
    }
}

// ---------------------------------------------------------------------------
// x_proj split-K MFMA (unchanged)
// ---------------------------------------------------------------------------
__global__ __launch_bounds__(256) void xproj_split(const ushort* __restrict__ xcbf,
                                                   const float* __restrict__ W,
                                                   float* __restrict__ xpart) {
    __shared__ ushort As[64 * 32];
    __shared__ float  Ws[16 * 32];
    const int tid  = threadIdx.x;
    const int lane = tid & 63;
    const int wave = tid >> 6;
    const int n0 = blockIdx.x * 16;
    const int m0 = blockIdx.y * 64;
    const int z  = blockIdx.z;
    const int wm = wave * 16;
    const int frow = lane & 15;
    const int fkg  = lane >> 4;
    const int kbase = z * KCHUNK;

    f32x4 acc = {};

    for (int it = 0; it < KCHUNK / 32; ++it) {
        const int k0 = kbase + it * 32;
        {
            int row = tid >> 2;
            int kc  = (tid & 3) * 8;
            __builtin_amdgcn_global_load_lds(
                (const __attribute__((address_space(1))) void*)(xcbf + (size_t)(m0 + row) * D_INNER + k0 + kc),
                (__attribute__((address_space(3))) void*)(As + tid * 8), 16, 0, 0);
        }
        if (tid < 128) {
            int row = tid >> 3;
            int kc  = (tid & 7) * 4;
            __builtin_amdgcn_global_load_lds(
                (const __attribute__((address_space(1))) void*)(W + (size_t)(n0 + row) * D_INNER + k0 + kc),
                (__attribute__((address_space(3))) void*)(Ws + tid * 4), 16, 0, 0);
        }
        __syncthreads();

        bf16x8 af = *(const bf16x8*)(As + (wm + frow) * 32 + fkg * 8);
        const float* bp = Ws + frow * 32 + fkg * 8;
        f32x4 lo = *(const f32x4*)bp;
        f32x4 hi = *(const f32x4*)(bp + 4);
        bf16x8 bb;
        bb[0] = (short)f2bf(lo[0]); bb[1] = (short)f2bf(lo[1]);
        bb[2] = (short)f2bf(lo[2]); bb[3] = (short)f2bf(lo[3]);
        bb[4] = (short)f2bf(hi[0]); bb[5] = (short)f2bf(hi[1]);
        bb[6] = (short)f2bf(hi[2]); bb[7] = (short)f2bf(hi[3]);
        acc = __builtin_amdgcn_mfma_f32_16x16x32_bf16(af, bb, acc, 0, 0, 0);
        __syncthreads();
    }

#pragma unroll
    for (int r = 0; r < 4; ++r) {
        int m = m0 + wm + fkg * 4 + r;
        int n = n0 + frow;
        xpart[((size_t)z * LSEQ + m) * XPROJ_N + n] = acc[r];
    }
}

// ---------------------------------------------------------------------------
// Reduce split-K partials (unchanged)
// ---------------------------------------------------------------------------
__global__ __launch_bounds__(256) void xreduce_kernel(const float* __restrict__ xpart,
                                                      float* __restrict__ dbl,
                                                      ushort* __restrict__ dtb) {
    int idx = blockIdx.x * 256 + threadIdx.x;
    if (idx >= LSEQ * XPROJ_N) return;
    int m = idx / XPROJ_N;
    int n = idx - m * XPROJ_N;
    float s = 0.f;
#pragma unroll
    for (int z = 0; z < KSPLIT; ++z)
        s += xpart[(size_t)z * LSEQ * XPROJ_N + idx];
    dbl[idx] = s;
    if (n < DT_RANK)      dtb[m * 128 + n] = f2bf(s);
    else if (n < 128)     dtb[m * 128 + n] = 0;
}

// ---------------------------------------------------------------------------
// dt_proj weight pad+convert (unchanged)
// ---------------------------------------------------------------------------
__global__ __launch_bounds__(256) void dtw_cvt_kernel(const float* __restrict__ w,
                                                      ushort* __restrict__ o) {
    int idx = blockIdx.x * 256 + threadIdx.x;
    if (idx >= D_INNER * 128) return;
    int r = idx >> 7, c = idx & 127;
    o[idx] = (c < DT_RANK) ? f2bf(w[(size_t)r * DT_RANK + c]) : (ushort)0;
}

// ---------------------------------------------------------------------------
// Causal depthwise conv + bias + SiLU (unchanged)
// ---------------------------------------------------------------------------
__global__ __launch_bounds__(256) void conv_silu_kernel(const float* __restrict__ xz,
                                                        const float* __restrict__ cw,
                                                        const float* __restrict__ cb,
                                                        float* __restrict__ xc,
                                                        ushort* __restrict__ xcbf) {
    int idx = blockIdx.x * 256 + threadIdx.x;
    if (idx >= LSEQ * D_INNER) return;
    int l = idx / D_INNER;
    int c = idx - l * D_INNER;
    const float4 w = *reinterpret_cast<const float4*>(cw + (size_t)c * D_CONV);
    float s = cb[c];
    const float wk[4] = {w.x, w.y, w.z, w.w};
#pragma unroll
    for (int k = 0; k < D_CONV; ++k) {
        int ll = l - (D_CONV - 1) + k;
        if (ll >= 0) s = fmaf(wk[k], xz[(size_t)ll * (2 * D_INNER) + c], s);
    }
    const float sig = 1.f / (1.f + __expf(-s));
    const float v = s * sig;
    xc[idx] = v;
    xcbf[idx] = f2bf(v);
}

// ---------------------------------------------------------------------------
// Chunk-parallel selective scan.
// S1: per (chunk c, channel d): P = prod(dA) over chunk, F = local final h.
// S2: sequential over chunks: Hin[c] = P[c-1]*Hin[c-1] + F[c-1], Hin[0]=0.
// S3: local scan seeded with Hin, emits y (C-dot + D-skip + z-gate) as bf16.
// Exact in fp32: dA in (0,1], products only decay.
// ---------------------------------------------------------------------------
__global__ __launch_bounds__(256) void scan_part1(const float* __restrict__ dt,
                                                  const float* __restrict__ xc,
                                                  const float* __restrict__ dbl,
                                                  const float* __restrict__ A_log,
                                                  float* __restrict__ P,
                                                  float* __restrict__ F) {
    const int d = blockIdx.x * 256 + threadIdx.x;
    const int c = blockIdx.y;
    __shared__ float Bs[SCL][D_STATE];
    {
        int t = threadIdx.x;          // 256 threads, SCL*16 = 256 elems
        int ll = t >> 4, s = t & 15;
        Bs[ll][s] = dbl[(size_t)(c * SCL + ll) * XPROJ_N + DT_RANK + s];
    }
    float A2[D_STATE], h[D_STATE], p[D_STATE];
#pragma unroll
    for (int s = 0; s < D_STATE; ++s) {
        A2[s] = -__expf(A_log[(size_t)d * D_STATE + s]) * 1.4426950408889634f;
        h[s] = 0.f; p[s] = 1.f;
    }
    __syncthreads();

    for (int li0 = 0; li0 < SCL; li0 += 4) {
        float dtv4[4], xcv4[4];
#pragma unroll
        for (int q = 0; q < 4; ++q) {
            const int l = c * SCL + li0 + q;
            dtv4[q] = dt[(size_t)l * D_INNER + d];
            xcv4[q] = xc[(size_t)l * D_INNER + d];
        }
#pragma unroll
        for (int q = 0; q < 4; ++q) {
            const int li = li0 + q;
            const float dtv = dtv4[q];
            const float coef = dtv * xcv4[q];
#pragma unroll
            for (int s = 0; s < D_STATE; ++s) {
                float e = exp2f(dtv * A2[s]);
                h[s] = fmaf(e, h[s], coef * Bs[li][s]);
                p[s] *= e;
            }
        }
    }
    float* Pp = P + ((size_t)c * D_INNER + d) * D_STATE;
    float* Fp = F + ((size_t)c * D_INNER + d) * D_STATE;
#pragma unroll
    for (int v = 0; v < 4; ++v) {
        *(f32x4*)(Pp + v * 4) = *(f32x4*)(p + v * 4);
        *(f32x4*)(Fp + v * 4) = *(f32x4*)(h + v * 4);
    }
}

__global__ __launch_bounds__(256) void scan_fix(const float* __restrict__ P,
                                                const float* __restrict__ F,
                                                float* __restrict__ Hin) {
    const int idx = blockIdx.x * 256 + threadIdx.x;   // (d, s) pair
    if (idx >= D_INNER * D_STATE) return;
    const size_t stride = (size_t)D_INNER * D_STATE;
    float h = 0.f;
#pragma unroll
    for (int c = 0; c < SCH; ++c) {
        Hin[c * stride + idx] = h;
        h = fmaf(P[c * stride + idx], h, F[c * stride + idx]);
    }
}

__global__ __launch_bounds__(256) void scan_part3(const float* __restrict__ dt,
                                                  const float* __restrict__ xc,
                                                  const float* __restrict__ dbl,
                                                  const float* __restrict__ A_log,
                                                  const float* __restrict__ Dp,
                                                  const float* __restrict__ xz,
                                                  const float* __restrict__ Hin,
                                                  ushort* __restrict__ ybf) {
    const int d = blockIdx.x * 256 + threadIdx.x;
    const int c = blockIdx.y;
    __shared__ float Bs[SCL][D_STATE];
    __shared__ float Cs[SCL][D_STATE];
    {
        int t = threadIdx.x;          // 512 elems, 2 per thread
        int ll = t >> 4, s = t & 15;
        Bs[ll][s] = dbl[(size_t)(c * SCL + ll) * XPROJ_N + DT_RANK + s];
        Cs[ll][s] = dbl[(size_t)(c * SCL + ll) * XPROJ_N + DT_RANK + D_STATE + s];
    }
    float A2[D_STATE], h[D_STATE];
#pragma unroll
    for (int s = 0; s < D_STATE; ++s)
        A2[s] = -__expf(A_log[(size_t)d * D_STATE + s]) * 1.4426950408889634f;
    {
        const float* Hp = Hin + ((size_t)c * D_INNER + d) * D_STATE;
#pragma unroll
        for (int v = 0; v < 4; ++v)
            *(f32x4*)(h + v * 4) = *(const f32x4*)(Hp + v * 4);
    }
    const float Dd = Dp[d];
    __syncthreads();

    for (int li0 = 0; li0 < SCL; li0 += 4) {
        float dtv4[4], xcv4[4], zv4[4];
#pragma unroll
        for (int q = 0; q < 4; ++q) {
            const int l = c * SCL + li0 + q;
            dtv4[q] = dt[(size_t)l * D_INNER + d];
            xcv4[q] = xc[(size_t)l * D_INNER + d];
            zv4[q]  = xz[(size_t)l * (2 * D_INNER) + D_INNER + d];
        }
#pragma unroll
        for (int q = 0; q < 4; ++q) {
            const int li = li0 + q;
            const float dtv = dtv4[q];
            const float xcv = xcv4[q];
            const float coef = dtv * xcv;
            float a0 = 0.f, a1 = 0.f, a2 = 0.f, a3 = 0.f;
#pragma unroll
            for (int s = 0; s < D_STATE; s += 4) {
                float e0 = exp2f(dtv * A2[s + 0]);
                float e1 = exp2f(dtv * A2[s + 1]);
                float e2 = exp2f(dtv * A2[s + 2]);
                float e3 = exp2f(dtv * A2[s + 3]);
                h[s + 0] = fmaf(e0, h[s + 0], coef * Bs[li][s + 0]);
                h[s + 1] = fmaf(e1, h[s + 1], coef * Bs[li][s + 1]);
                h[s + 2] = fmaf(e2, h[s + 2], coef * Bs[li][s + 2]);
                h[s + 3] = fmaf(e3, h[s + 3], coef * Bs[li][s + 3]);
                a0 = fmaf(h[s + 0], Cs[li][s + 0], a0);
                a1 = fmaf(h[s + 1], Cs[li][s + 1], a1);
                a2 = fmaf(h[s + 2], Cs[li][s + 2], a2);
                a3 = fmaf(h[s + 3], Cs[li][s + 3], a3);
            }
            const float zv = zv4[q];
            const float sig = 1.f / (1.f + __expf(-zv));
            const float y = ((a0 + a1) + (a2 + a3) + Dd * xcv) * (zv * sig);
            ybf[(size_t)(c * SCL + li) * D_INNER + d] = f2bf(y);
        }
    }
}

// ---------------------------------------------------------------------------
extern "C" void kernel_launch(void* const* d_in, const int* in_sizes, int n_in,
                              void* d_out, int out_size, void* d_ws, size_t ws_size,
                              hipStream_t stream) {
    const int*   ids       = (const int*)d_in[0];
    const float* embed     = (const float*)d_in[1];
    const float* in_proj_w = (const float*)d_in[2];
    const float* conv_w    = (const float*)d_in[3];
    const float* conv_b    = (const float*)d_in[4];
    const float* x_proj_w  = (const float*)d_in[5];
    const float* dt_proj_w = (const float*)d_in[6];
    const float* dt_proj_b = (const float*)d_in[7];
    const float* A_log     = (const float*)d_in[8];
    const float* D_skip    = (const float*)d_in[9];
    const float* out_proj_w= (const float*)d_in[10];
    const float* norm_w    = (const float*)d_in[11];
    const float* norm_b    = (const float*)d_in[12];
    const float* fin_w     = (const float*)d_in[13];
    const float* fin_b     = (const float*)d_in[14];
    float* out = (float*)d_out;

    float* ws = (float*)d_ws;
    float* res    = ws; ws += LSEQ * D_MODEL;
    float* hidden = ws; ws += LSEQ * D_MODEL;
    float* xz     = ws; ws += (size_t)LSEQ * 2 * D_INNER;
    float* xc     = ws; ws += (size_t)LSEQ * D_INNER;
    float* dbl    = ws; ws += LSEQ * XPROJ_N;
    float* dty    = ws; ws += (size_t)LSEQ * D_INNER;
    float* xpart  = ws; ws += (size_t)KSPLIT * LSEQ * XPROJ_N;
    float* Pbuf   = ws; ws += (size_t)SCH * D_INNER * D_STATE;
    float* Fbuf   = ws; ws += (size_t)SCH * D_INNER * D_STATE;
    float* HinB   = ws; ws += (size_t)SCH * D_INNER * D_STATE;
    ushort* hbf   = (ushort*)ws; ws += (LSEQ * D_MODEL) / 2;
    ushort* ybf   = (ushort*)ws; ws += (LSEQ * D_INNER) / 2;
    ushort* xcbf  = (ushort*)ws; ws += (LSEQ * D_INNER) / 2;
    ushort* dtb   = (ushort*)ws; ws += (LSEQ * 128) / 2;
    ushort* dtwbf = (ushort*)ws;

    embed_kernel<<<(LSEQ * D_MODEL + 255) / 256, 256, 0, stream>>>(ids, embed, res);

    for (int i = 0; i < NLAYER; ++i) {
        add_ln_kernel<<<LSEQ, 256, 0, stream>>>(
            res, hidden, norm_w + (size_t)i * D_MODEL, norm_b + (size_t)i * D_MODEL,
            nullptr, hbf, i > 0 ? 1 : 0);

        gemm_mfma<4, 0, 0><<<dim3(2 * D_INNER / 128, LSEQ / 128), 256, 0, stream>>>(
            hbf, D_MODEL, in_proj_w + (size_t)i * 2 * D_INNER * D_MODEL, xz,
            2 * D_INNER, D_MODEL, nullptr);

        conv_silu_kernel<<<(LSEQ * D_INNER + 255) / 256, 256, 0, stream>>>(
            xz, conv_w + (size_t)i * D_INNER * D_CONV, conv_b + (size_t)i * D_INNER,
            xc, xcbf);

        xproj_split<<<dim3(XPROJ_N / 16, LSEQ / 64, KSPLIT), 256, 0, stream>>>(
            xcbf, x_proj_w + (size_t)i * XPROJ_N * D_INNER, xpart);
        xreduce_kernel<<<(LSEQ * XPROJ_N + 255) / 256, 256, 0, stream>>>(xpart, dbl, dtb);

        dtw_cvt_kernel<<<(D_INNER * 128 + 255) / 256, 256, 0, stream>>>(
            dt_proj_w + (size_t)i * D_INNER * DT_RANK, dtwbf);
        gemm_mfma<2, 1, 1><<<dim3(D_INNER / 128, LSEQ / 64), 256, 0, stream>>>(
            dtb, 128, dtwbf, dty, D_INNER, 128, dt_proj_b + (size_t)i * D_INNER);

        scan_part1<<<dim3(D_INNER / 256, SCH), 256, 0, stream>>>(
            dty, xc, dbl, A_log + (size_t)i * D_INNER * D_STATE, Pbuf, Fbuf);
        scan_fix<<<(D_INNER * D_STATE + 255) / 256, 256, 0, stream>>>(Pbuf, Fbuf, HinB);
        scan_part3<<<dim3(D_INNER / 256, SCH), 256, 0, stream>>>(
            dty, xc, dbl, A_log + (size_t)i * D_INNER * D_STATE,
            D_skip + (size_t)i * D_INNER, xz, HinB, ybf);

        gemm_mfma<2, 0, 0><<<dim3(D_MODEL / 128, LSEQ / 64), 256, 0, stream>>>(
            ybf, D_INNER, out_proj_w + (size_t)i * D_MODEL * D_INNER, hidden,
            D_MODEL, D_INNER, nullptr);
    }

    add_ln_kernel<<<LSEQ, 256, 0, stream>>>(res, hidden, fin_w, fin_b, out, nullptr, 1);
}

// Round 5
// 1033.557 us; speedup vs baseline: 5.5041x; 1.4857x over previous
//
#include <hip/hip_runtime.h>
#include <hip/hip_bf16.h>
#include <math.h>

#define D_MODEL 1792
#define D_INNER 3584
#define D_STATE 16
#define D_CONV  4
#define DT_RANK 112
#define NLAYER  4
#define LSEQ    512
#define XPROJ_N (DT_RANK + 2 * D_STATE) /* 144 */
#define KSPLIT  8                        /* x_proj split-K factor */
#define KCHUNK  (D_INNER / KSPLIT)       /* 448 */
#define SCH     32                       /* scan chunks */
#define SCL     (LSEQ / SCH)             /* 16 steps per chunk */
#define INSPLIT 2                        /* in_proj K-split */
#define OUTSPLIT 4                       /* out_proj K-split */

typedef __attribute__((ext_vector_type(8))) short bf16x8;
typedef __attribute__((ext_vector_type(4))) float f32x4;

__device__ __forceinline__ ushort f2bf(float f) {
    unsigned u = __float_as_uint(f);
    unsigned r = (u + 0x7FFFu + ((u >> 16) & 1u)) >> 16;
    return (ushort)r;
}

// ---------------------------------------------------------------------------
// Embedding gather
// ---------------------------------------------------------------------------
__global__ __launch_bounds__(256) void embed_kernel(const int* __restrict__ ids,
                                                    const float* __restrict__ embed,
                                                    float* __restrict__ res) {
    int idx = blockIdx.x * 256 + threadIdx.x;
    if (idx >= LSEQ * D_MODEL) return;
    int l = idx / D_MODEL;
    int d = idx - l * D_MODEL;
    res[idx] = embed[(size_t)ids[l] * D_MODEL + d];
}

// ---------------------------------------------------------------------------
// (optional residual += sum of nsl partial slices) then LayerNorm.
// ---------------------------------------------------------------------------
__global__ __launch_bounds__(256) void add_ln_kernel(float* __restrict__ res,
                                                     const float* __restrict__ hidp,
                                                     const float* __restrict__ w,
                                                     const float* __restrict__ b,
                                                     float* __restrict__ out32,
                                                     ushort* __restrict__ out16,
                                                     int addFlag) {
    const int l = blockIdx.x;
    const int t = threadIdx.x;
    __shared__ float sbuf[8];
    float loc[7];
    float* row = res + (size_t)l * D_MODEL;

    float sum = 0.f;
#pragma unroll
    for (int i = 0; i < 7; ++i) {
        int d = t + i * 256;
        float v = row[d];
        if (addFlag) {
            float hv = 0.f;
#pragma unroll
            for (int z = 0; z < OUTSPLIT; ++z)
                hv += hidp[(size_t)z * LSEQ * D_MODEL + (size_t)l * D_MODEL + d];
            v += hv; row[d] = v;
        }
        loc[i] = v;
        sum += v;
    }
#pragma unroll
    for (int o = 32; o > 0; o >>= 1) sum += __shfl_down(sum, o, 64);
    if ((t & 63) == 0) sbuf[t >> 6] = sum;
    __syncthreads();
    if (t == 0) sbuf[4] = sbuf[0] + sbuf[1] + sbuf[2] + sbuf[3];
    __syncthreads();
    const float mu = sbuf[4] * (1.f / D_MODEL);

    float vs = 0.f;
#pragma unroll
    for (int i = 0; i < 7; ++i) { float d0 = loc[i] - mu; vs += d0 * d0; }
#pragma unroll
    for (int o = 32; o > 0; o >>= 1) vs += __shfl_down(vs, o, 64);
    __syncthreads();
    if ((t & 63) == 0) sbuf[t >> 6] = vs;
    __syncthreads();
    if (t == 0) sbuf[4] = sbuf[0] + sbuf[1] + sbuf[2] + sbuf[3];
    __syncthreads();
    const float rstd = rsqrtf(sbuf[4] * (1.f / D_MODEL) + 1e-5f);

#pragma unroll
    for (int i = 0; i < 7; ++i) {
        int d = t + i * 256;
        float v = (loc[i] - mu) * rstd * w[d] + b[d];
        if (out16) out16[(size_t)l * D_MODEL + d] = f2bf(v);
        else       out32[(size_t)l * D_MODEL + d] = v;
    }
}

// ---------------------------------------------------------------------------
// bf16 MFMA GEMM (NT), split-K over gridDim.z.
// C partial z: C[z*M*N + m*N + n] = sum_{k in chunk z} A[m,k]*W[n,k]
// Block: 64(M) x 128(N), BK=32, 4 waves, wave tile 32 x 64.
// WBF: W is bf16 (1) or fp32 converted in-register (0). ACT (softplus+bias)
// only valid with NSPLIT==1.
// ---------------------------------------------------------------------------
template<int WBF, int ACT, int NSPLIT>
__global__ __launch_bounds__(256) void gemm_mfma(const ushort* __restrict__ A, int lda,
                                                 const void* __restrict__ Wv,
                                                 float* __restrict__ C,
                                                 int N, int K,
                                                 const float* __restrict__ bias) {
    constexpr int BM = 64;
    constexpr int BK = 32;
    __shared__ ushort As[BM * BK];
    __shared__ __attribute__((aligned(16))) char Bs[WBF ? (128 * BK * 2) : (128 * BK * 4)];

    const int tid  = threadIdx.x;
    const int lane = tid & 63;
    const int wave = tid >> 6;
    const int m0 = blockIdx.y * BM;
    const int n0 = blockIdx.x * 128;
    const int wm = (wave >> 1) * 32;
    const int wn = (wave & 1) * 64;
    const int frow = lane & 15;
    const int fkg  = lane >> 4;
    const int kchunk = K / NSPLIT;
    const int kbase  = blockIdx.z * kchunk;
    const int M = gridDim.y * BM;

    f32x4 acc[2][4] = {};

    for (int it = 0; it < kchunk / BK; ++it) {
        const int k0 = kbase + it * BK;
        {   // A: 64 rows x 32 bf16 -> 256 chunks of 16 B
            int row = tid >> 2;
            int kc  = (tid & 3) * 8;
            __builtin_amdgcn_global_load_lds(
                (const __attribute__((address_space(1))) void*)(A + (size_t)(m0 + row) * lda + k0 + kc),
                (__attribute__((address_space(3))) void*)(As + tid * 8), 16, 0, 0);
        }
        if (WBF) {
            const ushort* W = (const ushort*)Wv;
#pragma unroll
            for (int i = 0; i < 2; ++i) {
                int c = tid + i * 256;
                int row = c >> 2;
                int kc  = (c & 3) * 8;
                __builtin_amdgcn_global_load_lds(
                    (const __attribute__((address_space(1))) void*)(W + (size_t)(n0 + row) * K + k0 + kc),
                    (__attribute__((address_space(3))) void*)(Bs + c * 16), 16, 0, 0);
            }
        } else {
            const float* W = (const float*)Wv;
#pragma unroll
            for (int i = 0; i < 4; ++i) {
                int c = tid + i * 256;
                int row = c >> 3;
                int kc  = (c & 7) * 4;
                __builtin_amdgcn_global_load_lds(
                    (const __attribute__((address_space(1))) void*)(W + (size_t)(n0 + row) * K + k0 + kc),
                    (__attribute__((address_space(3))) void*)(Bs + c * 16), 16, 0, 0);
            }
        }
        __syncthreads();

        bf16x8 af[2];
#pragma unroll
        for (int i = 0; i < 2; ++i)
            af[i] = *(const bf16x8*)(As + (wm + i * 16 + frow) * BK + fkg * 8);

#pragma unroll
        for (int j = 0; j < 4; ++j) {
            bf16x8 bb;
            if (WBF) {
                bb = *(const bf16x8*)((const ushort*)Bs + (wn + j * 16 + frow) * BK + fkg * 8);
            } else {
                const float* bp = (const float*)Bs + (wn + j * 16 + frow) * BK + fkg * 8;
                f32x4 lo = *(const f32x4*)bp;
                f32x4 hi = *(const f32x4*)(bp + 4);
                bb[0] = (short)f2bf(lo[0]); bb[1] = (short)f2bf(lo[1]);
                bb[2] = (short)f2bf(lo[2]); bb[3] = (short)f2bf(lo[3]);
                bb[4] = (short)f2bf(hi[0]); bb[5] = (short)f2bf(hi[1]);
                bb[6] = (short)f2bf(hi[2]); bb[7] = (short)f2bf(hi[3]);
            }
#pragma unroll
            for (int i = 0; i < 2; ++i)
                acc[i][j] = __builtin_amdgcn_mfma_f32_16x16x32_bf16(af[i], bb, acc[i][j], 0, 0, 0);
        }
        __syncthreads();
    }

    float bj[4];
    if (ACT) {
#pragma unroll
        for (int j = 0; j < 4; ++j) bj[j] = bias[n0 + wn + frow + j * 16];
    }

    float* Cz = C + (size_t)blockIdx.z * M * N;
#pragma unroll
    for (int i = 0; i < 2; ++i) {
#pragma unroll
        for (int r = 0; r < 4; ++r) {
            int m = m0 + wm + i * 16 + fkg * 4 + r;
            float* cp = Cz + (size_t)m * N + n0 + wn + frow;
#pragma unroll
            for (int j = 0; j < 4; ++j) {
                float v = acc[i][j][r];
                if (ACT) {
                    v += bj[j];
                    v = (v > 20.f) ? v : __logf(1.f + __expf(v));
                }
                cp[j * 16] = v;
            }
        }
    }
}

// ---------------------------------------------------------------------------
// x_proj split-K MFMA (unchanged)
// ---------------------------------------------------------------------------
__global__ __launch_bounds__(256) void xproj_split(const ushort* __restrict__ xcbf,
                                                   const float* __restrict__ W,
                                                   float* __restrict__ xpart) {
    __shared__ ushort As[64 * 32];
    __shared__ float  Ws[16 * 32];
    const int tid  = threadIdx.x;
    const int lane = tid & 63;
    const int wave = tid >> 6;
    const int n0 = blockIdx.x * 16;
    const int m0 = blockIdx.y * 64;
    const int z  = blockIdx.z;
    const int wm = wave * 16;
    const int frow = lane & 15;
    const int fkg  = lane >> 4;
    const int kbase = z * KCHUNK;

    f32x4 acc = {};

    for (int it = 0; it < KCHUNK / 32; ++it) {
        const int k0 = kbase + it * 32;
        {
            int row = tid >> 2;
            int kc  = (tid & 3) * 8;
            __builtin_amdgcn_global_load_lds(
                (const __attribute__((address_space(1))) void*)(xcbf + (size_t)(m0 + row) * D_INNER + k0 + kc),
                (__attribute__((address_space(3))) void*)(As + tid * 8), 16, 0, 0);
        }
        if (tid < 128) {
            int row = tid >> 3;
            int kc  = (tid & 7) * 4;
            __builtin_amdgcn_global_load_lds(
                (const __attribute__((address_space(1))) void*)(W + (size_t)(n0 + row) * D_INNER + k0 + kc),
                (__attribute__((address_space(3))) void*)(Ws + tid * 4), 16, 0, 0);
        }
        __syncthreads();

        bf16x8 af = *(const bf16x8*)(As + (wm + frow) * 32 + fkg * 8);
        const float* bp = Ws + frow * 32 + fkg * 8;
        f32x4 lo = *(const f32x4*)bp;
        f32x4 hi = *(const f32x4*)(bp + 4);
        bf16x8 bb;
        bb[0] = (short)f2bf(lo[0]); bb[1] = (short)f2bf(lo[1]);
        bb[2] = (short)f2bf(lo[2]); bb[3] = (short)f2bf(lo[3]);
        bb[4] = (short)f2bf(hi[0]); bb[5] = (short)f2bf(hi[1]);
        bb[6] = (short)f2bf(hi[2]); bb[7] = (short)f2bf(hi[3]);
        acc = __builtin_amdgcn_mfma_f32_16x16x32_bf16(af, bb, acc, 0, 0, 0);
        __syncthreads();
    }

#pragma unroll
    for (int r = 0; r < 4; ++r) {
        int m = m0 + wm + fkg * 4 + r;
        int n = n0 + frow;
        xpart[((size_t)z * LSEQ + m) * XPROJ_N + n] = acc[r];
    }
}

// ---------------------------------------------------------------------------
// Reduce x_proj split-K partials (unchanged)
// ---------------------------------------------------------------------------
__global__ __launch_bounds__(256) void xreduce_kernel(const float* __restrict__ xpart,
                                                      float* __restrict__ dbl,
                                                      ushort* __restrict__ dtb) {
    int idx = blockIdx.x * 256 + threadIdx.x;
    if (idx >= LSEQ * XPROJ_N) return;
    int m = idx / XPROJ_N;
    int n = idx - m * XPROJ_N;
    float s = 0.f;
#pragma unroll
    for (int z = 0; z < KSPLIT; ++z)
        s += xpart[(size_t)z * LSEQ * XPROJ_N + idx];
    dbl[idx] = s;
    if (n < DT_RANK)      dtb[m * 128 + n] = f2bf(s);
    else if (n < 128)     dtb[m * 128 + n] = 0;
}

// ---------------------------------------------------------------------------
// dt_proj weight pad+convert (unchanged)
// ---------------------------------------------------------------------------
__global__ __launch_bounds__(256) void dtw_cvt_kernel(const float* __restrict__ w,
                                                      ushort* __restrict__ o) {
    int idx = blockIdx.x * 256 + threadIdx.x;
    if (idx >= D_INNER * 128) return;
    int r = idx >> 7, c = idx & 127;
    o[idx] = (c < DT_RANK) ? f2bf(w[(size_t)r * DT_RANK + c]) : (ushort)0;
}

// ---------------------------------------------------------------------------
// Causal depthwise conv + bias + SiLU, reducing the INSPLIT xz partials.
// ---------------------------------------------------------------------------
__global__ __launch_bounds__(256) void conv_silu_kernel(const float* __restrict__ xzp,
                                                        const float* __restrict__ cw,
                                                        const float* __restrict__ cb,
                                                        float* __restrict__ xc,
                                                        ushort* __restrict__ xcbf) {
    const size_t SL = (size_t)LSEQ * 2 * D_INNER;
    int idx = blockIdx.x * 256 + threadIdx.x;
    if (idx >= LSEQ * D_INNER) return;
    int l = idx / D_INNER;
    int c = idx - l * D_INNER;
    const float4 w = *reinterpret_cast<const float4*>(cw + (size_t)c * D_CONV);
    float s = cb[c];
    const float wk[4] = {w.x, w.y, w.z, w.w};
#pragma unroll
    for (int k = 0; k < D_CONV; ++k) {
        int ll = l - (D_CONV - 1) + k;
        if (ll >= 0) {
            float v = xzp[(size_t)ll * (2 * D_INNER) + c]
                    + xzp[SL + (size_t)ll * (2 * D_INNER) + c];
            s = fmaf(wk[k], v, s);
        }
    }
    const float sig = 1.f / (1.f + __expf(-s));
    const float v = s * sig;
    xc[idx] = v;
    xcbf[idx] = f2bf(v);
}

// ---------------------------------------------------------------------------
// Chunk-parallel selective scan (S1 / fix / S3). S3 reduces xz z-partials.
// ---------------------------------------------------------------------------
__global__ __launch_bounds__(256) void scan_part1(const float* __restrict__ dt,
                                                  const float* __restrict__ xc,
                                                  const float* __restrict__ dbl,
                                                  const float* __restrict__ A_log,
                                                  float* __restrict__ P,
                                                  float* __restrict__ F) {
    const int d = blockIdx.x * 256 + threadIdx.x;
    const int c = blockIdx.y;
    __shared__ float Bs[SCL][D_STATE];
    {
        int t = threadIdx.x;
        int ll = t >> 4, s = t & 15;
        Bs[ll][s] = dbl[(size_t)(c * SCL + ll) * XPROJ_N + DT_RANK + s];
    }
    float A2[D_STATE], h[D_STATE], p[D_STATE];
#pragma unroll
    for (int s = 0; s < D_STATE; ++s) {
        A2[s] = -__expf(A_log[(size_t)d * D_STATE + s]) * 1.4426950408889634f;
        h[s] = 0.f; p[s] = 1.f;
    }
    __syncthreads();

    for (int li0 = 0; li0 < SCL; li0 += 4) {
        float dtv4[4], xcv4[4];
#pragma unroll
        for (int q = 0; q < 4; ++q) {
            const int l = c * SCL + li0 + q;
            dtv4[q] = dt[(size_t)l * D_INNER + d];
            xcv4[q] = xc[(size_t)l * D_INNER + d];
        }
#pragma unroll
        for (int q = 0; q < 4; ++q) {
            const int li = li0 + q;
            const float dtv = dtv4[q];
            const float coef = dtv * xcv4[q];
#pragma unroll
            for (int s = 0; s < D_STATE; ++s) {
                float e = exp2f(dtv * A2[s]);
                h[s] = fmaf(e, h[s], coef * Bs[li][s]);
                p[s] *= e;
            }
        }
    }
    float* Pp = P + ((size_t)c * D_INNER + d) * D_STATE;
    float* Fp = F + ((size_t)c * D_INNER + d) * D_STATE;
#pragma unroll
    for (int v = 0; v < 4; ++v) {
        *(f32x4*)(Pp + v * 4) = *(f32x4*)(p + v * 4);
        *(f32x4*)(Fp + v * 4) = *(f32x4*)(h + v * 4);
    }
}

__global__ __launch_bounds__(256) void scan_fix(const float* __restrict__ P,
                                                const float* __restrict__ F,
                                                float* __restrict__ Hin) {
    const int idx = blockIdx.x * 256 + threadIdx.x;
    if (idx >= D_INNER * D_STATE) return;
    const size_t stride = (size_t)D_INNER * D_STATE;
    float h = 0.f;
#pragma unroll
    for (int c = 0; c < SCH; ++c) {
        Hin[c * stride + idx] = h;
        h = fmaf(P[c * stride + idx], h, F[c * stride + idx]);
    }
}

__global__ __launch_bounds__(256) void scan_part3(const float* __restrict__ dt,
                                                  const float* __restrict__ xc,
                                                  const float* __restrict__ dbl,
                                                  const float* __restrict__ A_log,
                                                  const float* __restrict__ Dp,
                                                  const float* __restrict__ xzp,
                                                  const float* __restrict__ Hin,
                                                  ushort* __restrict__ ybf) {
    const size_t SL = (size_t)LSEQ * 2 * D_INNER;
    const int d = blockIdx.x * 256 + threadIdx.x;
    const int c = blockIdx.y;
    __shared__ float Bs[SCL][D_STATE];
    __shared__ float Cs[SCL][D_STATE];
    {
        int t = threadIdx.x;
        int ll = t >> 4, s = t & 15;
        Bs[ll][s] = dbl[(size_t)(c * SCL + ll) * XPROJ_N + DT_RANK + s];
        Cs[ll][s] = dbl[(size_t)(c * SCL + ll) * XPROJ_N + DT_RANK + D_STATE + s];
    }
    float A2[D_STATE], h[D_STATE];
#pragma unroll
    for (int s = 0; s < D_STATE; ++s)
        A2[s] = -__expf(A_log[(size_t)d * D_STATE + s]) * 1.4426950408889634f;
    {
        const float* Hp = Hin + ((size_t)c * D_INNER + d) * D_STATE;
#pragma unroll
        for (int v = 0; v < 4; ++v)
            *(f32x4*)(h + v * 4) = *(const f32x4*)(Hp + v * 4);
    }
    const float Dd = Dp[d];
    __syncthreads();

    for (int li0 = 0; li0 < SCL; li0 += 4) {
        float dtv4[4], xcv4[4], zv4[4];
#pragma unroll
        for (int q = 0; q < 4; ++q) {
            const int l = c * SCL + li0 + q;
            dtv4[q] = dt[(size_t)l * D_INNER + d];
            xcv4[q] = xc[(size_t)l * D_INNER + d];
            zv4[q]  = xzp[(size_t)l * (2 * D_INNER) + D_INNER + d]
                    + xzp[SL + (size_t)l * (2 * D_INNER) + D_INNER + d];
        }
#pragma unroll
        for (int q = 0; q < 4; ++q) {
            const int li = li0 + q;
            const float dtv = dtv4[q];
            const float xcv = xcv4[q];
            const float coef = dtv * xcv;
            float a0 = 0.f, a1 = 0.f, a2 = 0.f, a3 = 0.f;
#pragma unroll
            for (int s = 0; s < D_STATE; s += 4) {
                float e0 = exp2f(dtv * A2[s + 0]);
                float e1 = exp2f(dtv * A2[s + 1]);
                float e2 = exp2f(dtv * A2[s + 2]);
                float e3 = exp2f(dtv * A2[s + 3]);
                h[s + 0] = fmaf(e0, h[s + 0], coef * Bs[li][s + 0]);
                h[s + 1] = fmaf(e1, h[s + 1], coef * Bs[li][s + 1]);
                h[s + 2] = fmaf(e2, h[s + 2], coef * Bs[li][s + 2]);
                h[s + 3] = fmaf(e3, h[s + 3], coef * Bs[li][s + 3]);
                a0 = fmaf(h[s + 0], Cs[li][s + 0], a0);
                a1 = fmaf(h[s + 1], Cs[li][s + 1], a1);
                a2 = fmaf(h[s + 2], Cs[li][s + 2], a2);
                a3 = fmaf(h[s + 3], Cs[li][s + 3], a3);
            }
            const float zv = zv4[q];
            const float sig = 1.f / (1.f + __expf(-zv));
            const float y = ((a0 + a1) + (a2 + a3) + Dd * xcv) * (zv * sig);
            ybf[(size_t)(c * SCL + li) * D_INNER + d] = f2bf(y);
        }
    }
}

// ---------------------------------------------------------------------------
extern "C" void kernel_launch(void* const* d_in, const int* in_sizes, int n_in,
                              void* d_out, int out_size, void* d_ws, size_t ws_size,
                              hipStream_t stream) {
    const int*   ids       = (const int*)d_in[0];
    const float* embed     = (const float*)d_in[1];
    const float* in_proj_w = (const float*)d_in[2];
    const float* conv_w    = (const float*)d_in[3];
    const float* conv_b    = (const float*)d_in[4];
    const float* x_proj_w  = (const float*)d_in[5];
    const float* dt_proj_w = (const float*)d_in[6];
    const float* dt_proj_b = (const float*)d_in[7];
    const float* A_log     = (const float*)d_in[8];
    const float* D_skip    = (const float*)d_in[9];
    const float* out_proj_w= (const float*)d_in[10];
    const float* norm_w    = (const float*)d_in[11];
    const float* norm_b    = (const float*)d_in[12];
    const float* fin_w     = (const float*)d_in[13];
    const float* fin_b     = (const float*)d_in[14];
    float* out = (float*)d_out;

    float* ws = (float*)d_ws;
    float* res    = ws; ws += LSEQ * D_MODEL;
    float* xzp    = ws; ws += (size_t)INSPLIT * LSEQ * 2 * D_INNER;
    float* xc     = ws; ws += (size_t)LSEQ * D_INNER;
    float* dbl    = ws; ws += LSEQ * XPROJ_N;
    float* dty    = ws; ws += (size_t)LSEQ * D_INNER;
    float* xpart  = ws; ws += (size_t)KSPLIT * LSEQ * XPROJ_N;
    float* Pbuf   = ws; ws += (size_t)SCH * D_INNER * D_STATE;
    float* Fbuf   = ws; ws += (size_t)SCH * D_INNER * D_STATE;
    float* HinB   = ws; ws += (size_t)SCH * D_INNER * D_STATE;
    ushort* hbf   = (ushort*)ws; ws += (LSEQ * D_MODEL) / 2;
    ushort* ybf   = (ushort*)ws; ws += (LSEQ * D_INNER) / 2;
    ushort* xcbf  = (ushort*)ws; ws += (LSEQ * D_INNER) / 2;
    ushort* dtb   = (ushort*)ws; ws += (LSEQ * 128) / 2;
    ushort* dtwbf = (ushort*)ws;
    // out_proj partials alias P+F (2 x 7.34 MB = exactly OUTSPLIT x 512 x 1792
    // fp32). Lifetime: written after scan (P/F dead), consumed by next add_ln
    // before scan_part1 rewrites P/F. No overlap.
    float* outp = Pbuf;

    embed_kernel<<<(LSEQ * D_MODEL + 255) / 256, 256, 0, stream>>>(ids, embed, res);

    for (int i = 0; i < NLAYER; ++i) {
        add_ln_kernel<<<LSEQ, 256, 0, stream>>>(
            res, outp, norm_w + (size_t)i * D_MODEL, norm_b + (size_t)i * D_MODEL,
            nullptr, hbf, i > 0 ? 1 : 0);

        // in_proj: [512 x 1792] x [7168 x 1792]^T, split-K 2 -> xzp
        gemm_mfma<0, 0, INSPLIT><<<dim3(2 * D_INNER / 128, LSEQ / 64, INSPLIT), 256, 0, stream>>>(
            hbf, D_MODEL, in_proj_w + (size_t)i * 2 * D_INNER * D_MODEL, xzp,
            2 * D_INNER, D_MODEL, nullptr);

        conv_silu_kernel<<<(LSEQ * D_INNER + 255) / 256, 256, 0, stream>>>(
            xzp, conv_w + (size_t)i * D_INNER * D_CONV, conv_b + (size_t)i * D_INNER,
            xc, xcbf);

        xproj_split<<<dim3(XPROJ_N / 16, LSEQ / 64, KSPLIT), 256, 0, stream>>>(
            xcbf, x_proj_w + (size_t)i * XPROJ_N * D_INNER, xpart);
        xreduce_kernel<<<(LSEQ * XPROJ_N + 255) / 256, 256, 0, stream>>>(xpart, dbl, dtb);

        dtw_cvt_kernel<<<(D_INNER * 128 + 255) / 256, 256, 0, stream>>>(
            dt_proj_w + (size_t)i * D_INNER * DT_RANK, dtwbf);
        gemm_mfma<1, 1, 1><<<dim3(D_INNER / 128, LSEQ / 64, 1), 256, 0, stream>>>(
            dtb, 128, dtwbf, dty, D_INNER, 128, dt_proj_b + (size_t)i * D_INNER);

        scan_part1<<<dim3(D_INNER / 256, SCH), 256, 0, stream>>>(
            dty, xc, dbl, A_log + (size_t)i * D_INNER * D_STATE, Pbuf, Fbuf);
        scan_fix<<<(D_INNER * D_STATE + 255) / 256, 256, 0, stream>>>(Pbuf, Fbuf, HinB);
        scan_part3<<<dim3(D_INNER / 256, SCH), 256, 0, stream>>>(
            dty, xc, dbl, A_log + (size_t)i * D_INNER * D_STATE,
            D_skip + (size_t)i * D_INNER, xzp, HinB, ybf);

        // out_proj: [512 x 3584] x [1792 x 3584]^T, split-K 4 -> outp (P/F alias)
        gemm_mfma<0, 0, OUTSPLIT><<<dim3(D_MODEL / 128, LSEQ / 64, OUTSPLIT), 256, 0, stream>>>(
            ybf, D_INNER, out_proj_w + (size_t)i * D_MODEL * D_INNER, outp,
            D_MODEL, D_INNER, nullptr);
    }

    add_ln_kernel<<<LSEQ, 256, 0, stream>>>(res, outp, fin_w, fin_b, out, nullptr, 1);
}

// Round 6
// 967.657 us; speedup vs baseline: 5.8790x; 1.0681x over previous
//
#include <hip/hip_runtime.h>
#include <hip/hip_bf16.h>
#include <math.h>

#define D_MODEL 1792
#define D_INNER 3584
#define D_STATE 16
#define D_CONV  4
#define DT_RANK 112
#define NLAYER  4
#define LSEQ    512
#define XPROJ_N (DT_RANK + 2 * D_STATE) /* 144 */
#define KSPLIT  8                        /* x_proj split-K factor */
#define KCHUNK  (D_INNER / KSPLIT)       /* 448 */
#define SCH     32                       /* scan chunks */
#define SCL     (LSEQ / SCH)             /* 16 steps per chunk */
#define INSPLIT 2                        /* in_proj K-split */
#define OUTSPLIT 4                       /* out_proj K-split */

typedef __attribute__((ext_vector_type(8))) short bf16x8;
typedef __attribute__((ext_vector_type(8))) ushort u16x8;
typedef __attribute__((ext_vector_type(4))) float f32x4;

__device__ __forceinline__ ushort f2bf(float f) {
    unsigned u = __float_as_uint(f);
    unsigned r = (u + 0x7FFFu + ((u >> 16) & 1u)) >> 16;
    return (ushort)r;
}

// ---------------------------------------------------------------------------
// Bulk fp32 -> bf16 convert (8 elems/thread).
// ---------------------------------------------------------------------------
__global__ __launch_bounds__(256) void wcvt_kernel(const float* __restrict__ in,
                                                   ushort* __restrict__ out, int n8) {
    int idx = blockIdx.x * 256 + threadIdx.x;
    if (idx >= n8) return;
    const f32x4 a = *((const f32x4*)in + (size_t)idx * 2);
    const f32x4 b = *((const f32x4*)in + (size_t)idx * 2 + 1);
    u16x8 v;
    v[0] = f2bf(a[0]); v[1] = f2bf(a[1]); v[2] = f2bf(a[2]); v[3] = f2bf(a[3]);
    v[4] = f2bf(b[0]); v[5] = f2bf(b[1]); v[6] = f2bf(b[2]); v[7] = f2bf(b[3]);
    *(u16x8*)(out + (size_t)idx * 8) = v;
}

// ---------------------------------------------------------------------------
// dt_proj weights: [4][3584][112] fp32 -> [4][3584][128] bf16, zero-padded.
// 112 % 8 == 0, so each 8-group is fully-data or fully-pad.
// ---------------------------------------------------------------------------
__global__ __launch_bounds__(256) void dtcvt_kernel(const float* __restrict__ w,
                                                    ushort* __restrict__ o) {
    const int n8 = NLAYER * D_INNER * 128 / 8;
    int idx = blockIdx.x * 256 + threadIdx.x;
    if (idx >= n8) return;
    int col8 = idx & 15;          // 16 groups of 8 per 128-col row
    int row  = idx >> 4;          // global row across layers
    u16x8 v = {};
    if (col8 < DT_RANK / 8) {
        const float* p = w + (size_t)row * DT_RANK + col8 * 8;
        const f32x4 a = *(const f32x4*)p;
        const f32x4 b = *(const f32x4*)(p + 4);
        v[0] = f2bf(a[0]); v[1] = f2bf(a[1]); v[2] = f2bf(a[2]); v[3] = f2bf(a[3]);
        v[4] = f2bf(b[0]); v[5] = f2bf(b[1]); v[6] = f2bf(b[2]); v[7] = f2bf(b[3]);
    }
    *(u16x8*)(o + (size_t)idx * 8) = v;
}

// ---------------------------------------------------------------------------
// Embedding gather
// ---------------------------------------------------------------------------
__global__ __launch_bounds__(256) void embed_kernel(const int* __restrict__ ids,
                                                    const float* __restrict__ embed,
                                                    float* __restrict__ res) {
    int idx = blockIdx.x * 256 + threadIdx.x;
    if (idx >= LSEQ * D_MODEL) return;
    int l = idx / D_MODEL;
    int d = idx - l * D_MODEL;
    res[idx] = embed[(size_t)ids[l] * D_MODEL + d];
}

// ---------------------------------------------------------------------------
// (optional residual += sum of OUTSPLIT partial slices) then LayerNorm.
// ---------------------------------------------------------------------------
__global__ __launch_bounds__(256) void add_ln_kernel(float* __restrict__ res,
                                                     const float* __restrict__ hidp,
                                                     const float* __restrict__ w,
                                                     const float* __restrict__ b,
                                                     float* __restrict__ out32,
                                                     ushort* __restrict__ out16,
                                                     int addFlag) {
    const int l = blockIdx.x;
    const int t = threadIdx.x;
    __shared__ float sbuf[8];
    float loc[7];
    float* row = res + (size_t)l * D_MODEL;

    float sum = 0.f;
#pragma unroll
    for (int i = 0; i < 7; ++i) {
        int d = t + i * 256;
        float v = row[d];
        if (addFlag) {
            float hv = 0.f;
#pragma unroll
            for (int z = 0; z < OUTSPLIT; ++z)
                hv += hidp[(size_t)z * LSEQ * D_MODEL + (size_t)l * D_MODEL + d];
            v += hv; row[d] = v;
        }
        loc[i] = v;
        sum += v;
    }
#pragma unroll
    for (int o = 32; o > 0; o >>= 1) sum += __shfl_down(sum, o, 64);
    if ((t & 63) == 0) sbuf[t >> 6] = sum;
    __syncthreads();
    if (t == 0) sbuf[4] = sbuf[0] + sbuf[1] + sbuf[2] + sbuf[3];
    __syncthreads();
    const float mu = sbuf[4] * (1.f / D_MODEL);

    float vs = 0.f;
#pragma unroll
    for (int i = 0; i < 7; ++i) { float d0 = loc[i] - mu; vs += d0 * d0; }
#pragma unroll
    for (int o = 32; o > 0; o >>= 1) vs += __shfl_down(vs, o, 64);
    __syncthreads();
    if ((t & 63) == 0) sbuf[t >> 6] = vs;
    __syncthreads();
    if (t == 0) sbuf[4] = sbuf[0] + sbuf[1] + sbuf[2] + sbuf[3];
    __syncthreads();
    const float rstd = rsqrtf(sbuf[4] * (1.f / D_MODEL) + 1e-5f);

#pragma unroll
    for (int i = 0; i < 7; ++i) {
        int d = t + i * 256;
        float v = (loc[i] - mu) * rstd * w[d] + b[d];
        if (out16) out16[(size_t)l * D_MODEL + d] = f2bf(v);
        else       out32[(size_t)l * D_MODEL + d] = v;
    }
}

// ---------------------------------------------------------------------------
// bf16 MFMA GEMM (NT), pure-bf16 operands, split-K over gridDim.z.
// C partial z: C[z*M*N + m*N + n] = sum_{k in chunk z} A[m,k]*W[n,k]
// Block: 64(M) x 128(N), BK=32, 4 waves, wave tile 32 x 64. LDS = 12 KB.
// ACT (softplus+bias) only valid with NSPLIT==1.
// ---------------------------------------------------------------------------
template<int ACT, int NSPLIT>
__global__ __launch_bounds__(256) void gemm_mfma(const ushort* __restrict__ A, int lda,
                                                 const ushort* __restrict__ W,
                                                 float* __restrict__ C,
                                                 int N, int K,
                                                 const float* __restrict__ bias) {
    constexpr int BM = 64;
    constexpr int BK = 32;
    __shared__ ushort As[BM * BK];
    __shared__ ushort Bs[128 * BK];

    const int tid  = threadIdx.x;
    const int lane = tid & 63;
    const int wave = tid >> 6;
    const int m0 = blockIdx.y * BM;
    const int n0 = blockIdx.x * 128;
    const int wm = (wave >> 1) * 32;
    const int wn = (wave & 1) * 64;
    const int frow = lane & 15;
    const int fkg  = lane >> 4;
    const int kchunk = K / NSPLIT;
    const int kbase  = blockIdx.z * kchunk;
    const int M = gridDim.y * BM;

    f32x4 acc[2][4] = {};

    for (int it = 0; it < kchunk / BK; ++it) {
        const int k0 = kbase + it * BK;
        {   // A: 64 rows x 32 bf16 -> 256 chunks of 16 B
            int row = tid >> 2;
            int kc  = (tid & 3) * 8;
            __builtin_amdgcn_global_load_lds(
                (const __attribute__((address_space(1))) void*)(A + (size_t)(m0 + row) * lda + k0 + kc),
                (__attribute__((address_space(3))) void*)(As + tid * 8), 16, 0, 0);
        }
#pragma unroll
        for (int i = 0; i < 2; ++i) {  // B: 128 rows x 32 bf16 -> 512 chunks
            int c = tid + i * 256;
            int row = c >> 2;
            int kc  = (c & 3) * 8;
            __builtin_amdgcn_global_load_lds(
                (const __attribute__((address_space(1))) void*)(W + (size_t)(n0 + row) * K + k0 + kc),
                (__attribute__((address_space(3))) void*)(Bs + c * 8), 16, 0, 0);
        }
        __syncthreads();

        bf16x8 af[2];
#pragma unroll
        for (int i = 0; i < 2; ++i)
            af[i] = *(const bf16x8*)(As + (wm + i * 16 + frow) * BK + fkg * 8);

#pragma unroll
        for (int j = 0; j < 4; ++j) {
            bf16x8 bb = *(const bf16x8*)(Bs + (wn + j * 16 + frow) * BK + fkg * 8);
#pragma unroll
            for (int i = 0; i < 2; ++i)
                acc[i][j] = __builtin_amdgcn_mfma_f32_16x16x32_bf16(af[i], bb, acc[i][j], 0, 0, 0);
        }
        __syncthreads();
    }

    float bj[4];
    if (ACT) {
#pragma unroll
        for (int j = 0; j < 4; ++j) bj[j] = bias[n0 + wn + frow + j * 16];
    }

    float* Cz = C + (size_t)blockIdx.z * M * N;
#pragma unroll
    for (int i = 0; i < 2; ++i) {
#pragma unroll
        for (int r = 0; r < 4; ++r) {
            int m = m0 + wm + i * 16 + fkg * 4 + r;
            float* cp = Cz + (size_t)m * N + n0 + wn + frow;
#pragma unroll
            for (int j = 0; j < 4; ++j) {
                float v = acc[i][j][r];
                if (ACT) {
                    v += bj[j];
                    v = (v > 20.f) ? v : __logf(1.f + __expf(v));
                }
                cp[j * 16] = v;
            }
        }
    }
}

// ---------------------------------------------------------------------------
// x_proj split-K MFMA, bf16 weights.
// ---------------------------------------------------------------------------
__global__ __launch_bounds__(256) void xproj_split(const ushort* __restrict__ xcbf,
                                                   const ushort* __restrict__ W,
                                                   float* __restrict__ xpart) {
    __shared__ ushort As[64 * 32];
    __shared__ ushort Ws[16 * 32];
    const int tid  = threadIdx.x;
    const int lane = tid & 63;
    const int wave = tid >> 6;
    const int n0 = blockIdx.x * 16;
    const int m0 = blockIdx.y * 64;
    const int z  = blockIdx.z;
    const int wm = wave * 16;
    const int frow = lane & 15;
    const int fkg  = lane >> 4;
    const int kbase = z * KCHUNK;

    f32x4 acc = {};

    for (int it = 0; it < KCHUNK / 32; ++it) {
        const int k0 = kbase + it * 32;
        {
            int row = tid >> 2;
            int kc  = (tid & 3) * 8;
            __builtin_amdgcn_global_load_lds(
                (const __attribute__((address_space(1))) void*)(xcbf + (size_t)(m0 + row) * D_INNER + k0 + kc),
                (__attribute__((address_space(3))) void*)(As + tid * 8), 16, 0, 0);
        }
        if (tid < 64) {   // W: 16 rows x 32 bf16 -> 64 chunks of 16 B
            int row = tid >> 2;
            int kc  = (tid & 3) * 8;
            __builtin_amdgcn_global_load_lds(
                (const __attribute__((address_space(1))) void*)(W + (size_t)(n0 + row) * D_INNER + k0 + kc),
                (__attribute__((address_space(3))) void*)(Ws + tid * 8), 16, 0, 0);
        }
        __syncthreads();

        bf16x8 af = *(const bf16x8*)(As + (wm + frow) * 32 + fkg * 8);
        bf16x8 bb = *(const bf16x8*)(Ws + frow * 32 + fkg * 8);
        acc = __builtin_amdgcn_mfma_f32_16x16x32_bf16(af, bb, acc, 0, 0, 0);
        __syncthreads();
    }

#pragma unroll
    for (int r = 0; r < 4; ++r) {
        int m = m0 + wm + fkg * 4 + r;
        int n = n0 + frow;
        xpart[((size_t)z * LSEQ + m) * XPROJ_N + n] = acc[r];
    }
}

// ---------------------------------------------------------------------------
// Reduce x_proj split-K partials
// ---------------------------------------------------------------------------
__global__ __launch_bounds__(256) void xreduce_kernel(const float* __restrict__ xpart,
                                                      float* __restrict__ dbl,
                                                      ushort* __restrict__ dtb) {
    int idx = blockIdx.x * 256 + threadIdx.x;
    if (idx >= LSEQ * XPROJ_N) return;
    int m = idx / XPROJ_N;
    int n = idx - m * XPROJ_N;
    float s = 0.f;
#pragma unroll
    for (int z = 0; z < KSPLIT; ++z)
        s += xpart[(size_t)z * LSEQ * XPROJ_N + idx];
    dbl[idx] = s;
    if (n < DT_RANK)      dtb[m * 128 + n] = f2bf(s);
    else if (n < 128)     dtb[m * 128 + n] = 0;
}

// ---------------------------------------------------------------------------
// Causal depthwise conv + bias + SiLU, reducing the INSPLIT xz partials.
// ---------------------------------------------------------------------------
__global__ __launch_bounds__(256) void conv_silu_kernel(const float* __restrict__ xzp,
                                                        const float* __restrict__ cw,
                                                        const float* __restrict__ cb,
                                                        float* __restrict__ xc,
                                                        ushort* __restrict__ xcbf) {
    const size_t SL = (size_t)LSEQ * 2 * D_INNER;
    int idx = blockIdx.x * 256 + threadIdx.x;
    if (idx >= LSEQ * D_INNER) return;
    int l = idx / D_INNER;
    int c = idx - l * D_INNER;
    const float4 w = *reinterpret_cast<const float4*>(cw + (size_t)c * D_CONV);
    float s = cb[c];
    const float wk[4] = {w.x, w.y, w.z, w.w};
#pragma unroll
    for (int k = 0; k < D_CONV; ++k) {
        int ll = l - (D_CONV - 1) + k;
        if (ll >= 0) {
            float v = xzp[(size_t)ll * (2 * D_INNER) + c]
                    + xzp[SL + (size_t)ll * (2 * D_INNER) + c];
            s = fmaf(wk[k], v, s);
        }
    }
    const float sig = 1.f / (1.f + __expf(-s));
    const float v = s * sig;
    xc[idx] = v;
    xcbf[idx] = f2bf(v);
}

// ---------------------------------------------------------------------------
// Chunk-parallel selective scan (S1 / fix / S3). S3 reduces xz z-partials.
// ---------------------------------------------------------------------------
__global__ __launch_bounds__(256) void scan_part1(const float* __restrict__ dt,
                                                  const float* __restrict__ xc,
                                                  const float* __restrict__ dbl,
                                                  const float* __restrict__ A_log,
                                                  float* __restrict__ P,
                                                  float* __restrict__ F) {
    const int d = blockIdx.x * 256 + threadIdx.x;
    const int c = blockIdx.y;
    __shared__ float Bs[SCL][D_STATE];
    {
        int t = threadIdx.x;
        int ll = t >> 4, s = t & 15;
        Bs[ll][s] = dbl[(size_t)(c * SCL + ll) * XPROJ_N + DT_RANK + s];
    }
    float A2[D_STATE], h[D_STATE], p[D_STATE];
#pragma unroll
    for (int s = 0; s < D_STATE; ++s) {
        A2[s] = -__expf(A_log[(size_t)d * D_STATE + s]) * 1.4426950408889634f;
        h[s] = 0.f; p[s] = 1.f;
    }
    __syncthreads();

    for (int li0 = 0; li0 < SCL; li0 += 4) {
        float dtv4[4], xcv4[4];
#pragma unroll
        for (int q = 0; q < 4; ++q) {
            const int l = c * SCL + li0 + q;
            dtv4[q] = dt[(size_t)l * D_INNER + d];
            xcv4[q] = xc[(size_t)l * D_INNER + d];
        }
#pragma unroll
        for (int q = 0; q < 4; ++q) {
            const int li = li0 + q;
            const float dtv = dtv4[q];
            const float coef = dtv * xcv4[q];
#pragma unroll
            for (int s = 0; s < D_STATE; ++s) {
                float e = exp2f(dtv * A2[s]);
                h[s] = fmaf(e, h[s], coef * Bs[li][s]);
                p[s] *= e;
            }
        }
    }
    float* Pp = P + ((size_t)c * D_INNER + d) * D_STATE;
    float* Fp = F + ((size_t)c * D_INNER + d) * D_STATE;
#pragma unroll
    for (int v = 0; v < 4; ++v) {
        *(f32x4*)(Pp + v * 4) = *(f32x4*)(p + v * 4);
        *(f32x4*)(Fp + v * 4) = *(f32x4*)(h + v * 4);
    }
}

__global__ __launch_bounds__(256) void scan_fix(const float* __restrict__ P,
                                                const float* __restrict__ F,
                                                float* __restrict__ Hin) {
    const int idx = blockIdx.x * 256 + threadIdx.x;
    if (idx >= D_INNER * D_STATE) return;
    const size_t stride = (size_t)D_INNER * D_STATE;
    float h = 0.f;
#pragma unroll
    for (int c = 0; c < SCH; ++c) {
        Hin[c * stride + idx] = h;
        h = fmaf(P[c * stride + idx], h, F[c * stride + idx]);
    }
}

__global__ __launch_bounds__(256) void scan_part3(const float* __restrict__ dt,
                                                  const float* __restrict__ xc,
                                                  const float* __restrict__ dbl,
                                                  const float* __restrict__ A_log,
                                                  const float* __restrict__ Dp,
                                                  const float* __restrict__ xzp,
                                                  const float* __restrict__ Hin,
                                                  ushort* __restrict__ ybf) {
    const size_t SL = (size_t)LSEQ * 2 * D_INNER;
    const int d = blockIdx.x * 256 + threadIdx.x;
    const int c = blockIdx.y;
    __shared__ float Bs[SCL][D_STATE];
    __shared__ float Cs[SCL][D_STATE];
    {
        int t = threadIdx.x;
        int ll = t >> 4, s = t & 15;
        Bs[ll][s] = dbl[(size_t)(c * SCL + ll) * XPROJ_N + DT_RANK + s];
        Cs[ll][s] = dbl[(size_t)(c * SCL + ll) * XPROJ_N + DT_RANK + D_STATE + s];
    }
    float A2[D_STATE], h[D_STATE];
#pragma unroll
    for (int s = 0; s < D_STATE; ++s)
        A2[s] = -__expf(A_log[(size_t)d * D_STATE + s]) * 1.4426950408889634f;
    {
        const float* Hp = Hin + ((size_t)c * D_INNER + d) * D_STATE;
#pragma unroll
        for (int v = 0; v < 4; ++v)
            *(f32x4*)(h + v * 4) = *(const f32x4*)(Hp + v * 4);
    }
    const float Dd = Dp[d];
    __syncthreads();

    for (int li0 = 0; li0 < SCL; li0 += 4) {
        float dtv4[4], xcv4[4], zv4[4];
#pragma unroll
        for (int q = 0; q < 4; ++q) {
            const int l = c * SCL + li0 + q;
            dtv4[q] = dt[(size_t)l * D_INNER + d];
            xcv4[q] = xc[(size_t)l * D_INNER + d];
            zv4[q]  = xzp[(size_t)l * (2 * D_INNER) + D_INNER + d]
                    + xzp[SL + (size_t)l * (2 * D_INNER) + D_INNER + d];
        }
#pragma unroll
        for (int q = 0; q < 4; ++q) {
            const int li = li0 + q;
            const float dtv = dtv4[q];
            const float xcv = xcv4[q];
            const float coef = dtv * xcv;
            float a0 = 0.f, a1 = 0.f, a2 = 0.f, a3 = 0.f;
#pragma unroll
            for (int s = 0; s < D_STATE; s += 4) {
                float e0 = exp2f(dtv * A2[s + 0]);
                float e1 = exp2f(dtv * A2[s + 1]);
                float e2 = exp2f(dtv * A2[s + 2]);
                float e3 = exp2f(dtv * A2[s + 3]);
                h[s + 0] = fmaf(e0, h[s + 0], coef * Bs[li][s + 0]);
                h[s + 1] = fmaf(e1, h[s + 1], coef * Bs[li][s + 1]);
                h[s + 2] = fmaf(e2, h[s + 2], coef * Bs[li][s + 2]);
                h[s + 3] = fmaf(e3, h[s + 3], coef * Bs[li][s + 3]);
                a0 = fmaf(h[s + 0], Cs[li][s + 0], a0);
                a1 = fmaf(h[s + 1], Cs[li][s + 1], a1);
                a2 = fmaf(h[s + 2], Cs[li][s + 2], a2);
                a3 = fmaf(h[s + 3], Cs[li][s + 3], a3);
            }
            const float zv = zv4[q];
            const float sig = 1.f / (1.f + __expf(-zv));
            const float y = ((a0 + a1) + (a2 + a3) + Dd * xcv) * (zv * sig);
            ybf[(size_t)(c * SCL + li) * D_INNER + d] = f2bf(y);
        }
    }
}

// ---------------------------------------------------------------------------
extern "C" void kernel_launch(void* const* d_in, const int* in_sizes, int n_in,
                              void* d_out, int out_size, void* d_ws, size_t ws_size,
                              hipStream_t stream) {
    const int*   ids       = (const int*)d_in[0];
    const float* embed     = (const float*)d_in[1];
    const float* in_proj_w = (const float*)d_in[2];
    const float* conv_w    = (const float*)d_in[3];
    const float* conv_b    = (const float*)d_in[4];
    const float* x_proj_w  = (const float*)d_in[5];
    const float* dt_proj_w = (const float*)d_in[6];
    const float* dt_proj_b = (const float*)d_in[7];
    const float* A_log     = (const float*)d_in[8];
    const float* D_skip    = (const float*)d_in[9];
    const float* out_proj_w= (const float*)d_in[10];
    const float* norm_w    = (const float*)d_in[11];
    const float* norm_b    = (const float*)d_in[12];
    const float* fin_w     = (const float*)d_in[13];
    const float* fin_b     = (const float*)d_in[14];
    float* out = (float*)d_out;

    float* ws = (float*)d_ws;
    float* res    = ws; ws += LSEQ * D_MODEL;
    float* xzp    = ws; ws += (size_t)INSPLIT * LSEQ * 2 * D_INNER;
    float* xc     = ws; ws += (size_t)LSEQ * D_INNER;
    float* dbl    = ws; ws += LSEQ * XPROJ_N;
    float* dty    = ws; ws += (size_t)LSEQ * D_INNER;
    float* xpart  = ws; ws += (size_t)KSPLIT * LSEQ * XPROJ_N;
    float* Pbuf   = ws; ws += (size_t)SCH * D_INNER * D_STATE;
    float* Fbuf   = ws; ws += (size_t)SCH * D_INNER * D_STATE;
    float* HinB   = ws; ws += (size_t)SCH * D_INNER * D_STATE;
    ushort* hbf   = (ushort*)ws; ws += (LSEQ * D_MODEL) / 2;
    ushort* ybf   = (ushort*)ws; ws += (LSEQ * D_INNER) / 2;
    ushort* xcbf  = (ushort*)ws; ws += (LSEQ * D_INNER) / 2;
    ushort* dtb   = (ushort*)ws; ws += (LSEQ * 128) / 2;
    // bf16 weights (all 4 layers, converted once per call)
    ushort* inw_bf  = (ushort*)ws; ws += (size_t)NLAYER * 2 * D_INNER * D_MODEL / 2;
    ushort* outw_bf = (ushort*)ws; ws += (size_t)NLAYER * D_MODEL * D_INNER / 2;
    ushort* xw_bf   = (ushort*)ws; ws += (size_t)NLAYER * XPROJ_N * D_INNER / 2;
    ushort* dtw_bf  = (ushort*)ws; ws += (size_t)NLAYER * D_INNER * 128 / 2;
    // out_proj partials alias P+F (2 x 7.34 MB >= OUTSPLIT x 512 x 1792 fp32).
    float* outp = Pbuf;

    // --- one-time per call: weights -> bf16 ---
    {
        int n8_in  = NLAYER * 2 * D_INNER * D_MODEL / 8;
        int n8_out = NLAYER * D_MODEL * D_INNER / 8;
        int n8_x   = NLAYER * XPROJ_N * D_INNER / 8;
        int n8_dt  = NLAYER * D_INNER * 128 / 8;
        wcvt_kernel<<<(n8_in + 255) / 256, 256, 0, stream>>>(in_proj_w, inw_bf, n8_in);
        wcvt_kernel<<<(n8_out + 255) / 256, 256, 0, stream>>>(out_proj_w, outw_bf, n8_out);
        wcvt_kernel<<<(n8_x + 255) / 256, 256, 0, stream>>>(x_proj_w, xw_bf, n8_x);
        dtcvt_kernel<<<(n8_dt + 255) / 256, 256, 0, stream>>>(dt_proj_w, dtw_bf);
    }

    embed_kernel<<<(LSEQ * D_MODEL + 255) / 256, 256, 0, stream>>>(ids, embed, res);

    for (int i = 0; i < NLAYER; ++i) {
        add_ln_kernel<<<LSEQ, 256, 0, stream>>>(
            res, outp, norm_w + (size_t)i * D_MODEL, norm_b + (size_t)i * D_MODEL,
            nullptr, hbf, i > 0 ? 1 : 0);

        // in_proj: [512 x 1792] x [7168 x 1792]^T, split-K 2 -> xzp
        gemm_mfma<0, INSPLIT><<<dim3(2 * D_INNER / 128, LSEQ / 64, INSPLIT), 256, 0, stream>>>(
            hbf, D_MODEL, inw_bf + (size_t)i * 2 * D_INNER * D_MODEL, xzp,
            2 * D_INNER, D_MODEL, nullptr);

        conv_silu_kernel<<<(LSEQ * D_INNER + 255) / 256, 256, 0, stream>>>(
            xzp, conv_w + (size_t)i * D_INNER * D_CONV, conv_b + (size_t)i * D_INNER,
            xc, xcbf);

        xproj_split<<<dim3(XPROJ_N / 16, LSEQ / 64, KSPLIT), 256, 0, stream>>>(
            xcbf, xw_bf + (size_t)i * XPROJ_N * D_INNER, xpart);
        xreduce_kernel<<<(LSEQ * XPROJ_N + 255) / 256, 256, 0, stream>>>(xpart, dbl, dtb);

        gemm_mfma<1, 1><<<dim3(D_INNER / 128, LSEQ / 64, 1), 256, 0, stream>>>(
            dtb, 128, dtw_bf + (size_t)i * D_INNER * 128, dty,
            D_INNER, 128, dt_proj_b + (size_t)i * D_INNER);

        scan_part1<<<dim3(D_INNER / 256, SCH), 256, 0, stream>>>(
            dty, xc, dbl, A_log + (size_t)i * D_INNER * D_STATE, Pbuf, Fbuf);
        scan_fix<<<(D_INNER * D_STATE + 255) / 256, 256, 0, stream>>>(Pbuf, Fbuf, HinB);
        scan_part3<<<dim3(D_INNER / 256, SCH), 256, 0, stream>>>(
            dty, xc, dbl, A_log + (size_t)i * D_INNER * D_STATE,
            D_skip + (size_t)i * D_INNER, xzp, HinB, ybf);

        // out_proj: [512 x 3584] x [1792 x 3584]^T, split-K 4 -> outp (P/F alias)
        gemm_mfma<0, OUTSPLIT><<<dim3(D_MODEL / 128, LSEQ / 64, OUTSPLIT), 256, 0, stream>>>(
            ybf, D_INNER, outw_bf + (size_t)i * D_MODEL * D_INNER, outp,
            D_MODEL, D_INNER, nullptr);
    }

    add_ln_kernel<<<LSEQ, 256, 0, stream>>>(res, outp, fin_w, fin_b, out, nullptr, 1);
}